// Round 1
// baseline (569.051 us; speedup 1.0000x reference)
//
#include <hip/hip_runtime.h>
#include <hip/hip_bf16.h>
#include <math.h>

// Transformer block. Round 12: all four GEMMs moved to a 256xBN 8-phase
// pipelined core (T2 LDS swizzle + T3/T4 counted-vmcnt deep stage stream +
// T5 setprio). Old 2-phase cores (m97-style) were 10% MfmaUtil with 8-way
// LDS bank conflicts; 8-phase template is the verified fix (learn_hip m201).
// Attention / LN / transpose unchanged from Round 11.
// D_MODEL=1024, N_HEAD=16, D_HEAD=64, EXP=4, B=2, T=2048, EPS=1e-5

#define D_MODEL 1024
#define N_HEAD  16
#define D_HEAD  64
#define SEQ_T   2048
#define BATCH   2
#define NROWS   (BATCH * SEQ_T)   // 4096
#define C3      (3 * D_MODEL)     // 3072
#define D_FF    (4 * D_MODEL)     // 4096

typedef __bf16 bf16x8 __attribute__((ext_vector_type(8)));
typedef __bf16 bf16x4t __attribute__((ext_vector_type(4)));
typedef short  s16x4  __attribute__((ext_vector_type(4)));
typedef float  f32x4  __attribute__((ext_vector_type(4)));

// 16x16x16 bf16 MFMA: builtin name differs across ROCm versions.
__device__ __forceinline__ f32x4 mfma16_bf16(s16x4 a, s16x4 b, f32x4 c)
{
#if __has_builtin(__builtin_amdgcn_mfma_f32_16x16x16_bf16)
    return __builtin_amdgcn_mfma_f32_16x16x16_bf16(
        __builtin_bit_cast(bf16x4t, a), __builtin_bit_cast(bf16x4t, b), c, 0, 0, 0);
#else
    return __builtin_amdgcn_mfma_f32_16x16x16bf16_1k(a, b, c, 0, 0, 0);
#endif
}

// ---------------------------------------------------------------- LayerNorm
__global__ __launch_bounds__(256) void ln_kernel(
    const float* __restrict__ in, const float* __restrict__ w,
    const float* __restrict__ b, __hip_bfloat16* __restrict__ out, int D)
{
    const int row = blockIdx.x;
    const int tid = threadIdx.x;
    const float* x = in + (size_t)row * D;

    float s = 0.f, s2 = 0.f;
    for (int i = tid; i < D; i += 256) {
        float v = x[i];
        s += v; s2 += v * v;
    }
    __shared__ float rs[256], rs2[256];
    rs[tid] = s; rs2[tid] = s2;
    __syncthreads();
    for (int off = 128; off > 0; off >>= 1) {
        if (tid < off) { rs[tid] += rs[tid + off]; rs2[tid] += rs2[tid + off]; }
        __syncthreads();
    }
    const float mu   = rs[0] / D;
    const float var  = rs2[0] / D - mu * mu;
    const float rstd = rsqrtf(var + 1e-5f);

    __hip_bfloat16* o = out + (size_t)row * D;
    for (int i = tid; i < D; i += 256)
        o[i] = __float2bfloat16((x[i] - mu) * rstd * w[i] + b[i]);
}

// -------------------------------- merged weight transpose + bf16 cast (x4)
__global__ __launch_bounds__(256) void transpose_all_kernel(
    const float* __restrict__ attn_w, const float* __restrict__ proj_w,
    const float* __restrict__ fc_w,   const float* __restrict__ fc2_w,
    __hip_bfloat16* __restrict__ attn_wt, __hip_bfloat16* __restrict__ proj_wt,
    __hip_bfloat16* __restrict__ fc_wt,   __hip_bfloat16* __restrict__ fc2_wt)
{
    __shared__ float t[32][33];
    int tb = blockIdx.x;
    const float* W; __hip_bfloat16* Wt; int K, N;
    if (tb < 3072)      { W = attn_w; Wt = attn_wt; K = D_MODEL; N = C3; }
    else if (tb < 4096) { tb -= 3072; W = proj_w; Wt = proj_wt; K = D_MODEL; N = D_MODEL; }
    else if (tb < 8192) { tb -= 4096; W = fc_w;   Wt = fc_wt;   K = D_MODEL; N = D_FF; }
    else                { tb -= 8192; W = fc2_w;  Wt = fc2_wt;  K = D_FF;    N = D_MODEL; }
    const int ntx = N >> 5;
    const int k0 = (tb / ntx) * 32;
    const int n0 = (tb % ntx) * 32;

    const int tx = threadIdx.x & 31;
    const int ty = threadIdx.x >> 5;
#pragma unroll
    for (int i = 0; i < 4; ++i)
        t[ty + 8 * i][tx] = W[(size_t)(k0 + ty + 8 * i) * N + n0 + tx];
    __syncthreads();
#pragma unroll
    for (int i = 0; i < 4; ++i)
        Wt[(size_t)(n0 + ty + 8 * i) * K + k0 + tx] =
            __float2bfloat16(t[tx][ty + 8 * i]);
}

// ----------------------------------------------------------- helpers
__device__ __forceinline__ void async16(const __hip_bfloat16* g, __hip_bfloat16* l)
{
    __builtin_amdgcn_global_load_lds(
        (const __attribute__((address_space(1))) void*)g,
        (__attribute__((address_space(3))) void*)l, 16, 0, 0);
}

__device__ __forceinline__ float gelu_exact(float v)
{
    return 0.5f * v * (1.0f + erff(v * 0.70710678118654752f));
}

// ================= 8-phase 256xBN GEMM core (T2+T3+T4+T5) =================
// BM=256 rows, BK=64 (two kh-slices of 32 cols), 8 waves = WM x WN
// (WM = 8/WN), per-wave output (256/WM) x 64, 512 threads.
// LDS: Asl[par][kh][256*32], Bsl[par][kh][BN*32]; slice rows = 32 elems
// (64 B).  T2 swizzle: 16B-granule g stores source granule g ^ ((row>>1)&3)
// -> every ds_read_b128 is 2-way (free).  Applied both-sides (rule #21):
// linear global_load_lds dest + pre-swizzled per-lane GLOBAL source column
// + swizzled ds_read column.
// Stage stream (one slice per phase, 2-K-tile lead, vmcnt never 0):
//   t.p0: Bsl[par^1][1] <- tile t+1   (region last read at (t-1).p3)
//   t.p1: Asl[par][0]   <- tile t+2   (last read t.p0)
//   t.p2: Bsl[par][0]   <- tile t+2   (last read t.p1)
//   t.p3: Asl[par][1]   <- tile t+2   (last read t.p2)
// Each overwrite is >=1 full barrier after the region's last read; the
// post-MFMA barrier guarantees all waves' ds_reads have sampled (m201).
// Counted vmcnt at p0/p2 only: allowed outstanding = 3 A-slices + 2
// B-slices = 10 loads (WN=4) / 8 loads (WN=2).  sched_barrier(0) after
// each vmcnt pins the ds_reads behind it (rule #18).

template<int NL>
__device__ __forceinline__ void stage_slice(
    const __hip_bfloat16* __restrict__ g, int K,
    __hip_bfloat16* __restrict__ ldst, int tid)
{
#pragma unroll
    for (int i = 0; i < NL; ++i)
        async16(g + (size_t)(i * 128) * K, ldst + i * 4096 + tid * 8);
}

template<int WN>
__device__ __forceinline__ void gemm8_core(
    const __hip_bfloat16* __restrict__ A,
    const __hip_bfloat16* __restrict__ Bt,
    int K, int row0, int col0,
    f32x4 (&acc)[2 * WN][4])
{
    constexpr int MI  = 2 * WN;       // m-fragments per wave (8 or 4)
    constexpr int NLB = WN / 2;       // loads per B slice (2 or 1)
    constexpr int VMN = (WN == 4) ? 10 : 8;
    constexpr int WVM = 0x0F70 | VMN; // lgkmcnt=15, expcnt=7, vmcnt=VMN

    __shared__ __align__(16) __hip_bfloat16 Asl[2][2][256 * 32];
    __shared__ __align__(16) __hip_bfloat16 Bsl[2][2][WN * 64 * 32];

    const int tid  = threadIdx.x;
    const int wv   = tid >> 6;
    const int lane = tid & 63;
    const int ln15 = lane & 15;
    const int lq   = lane >> 4;
    const int wr   = wv / WN;
    const int wc   = wv % WN;
    // read-side swizzled column (elems) inside a 32-col slice row
    const int rcol = (lq ^ ((ln15 >> 1) & 3)) * 8;
    // stage-side: dst granule tid&3, row tid>>2 -> source granule XOR
    const int ssw  = ((tid & 3) ^ ((tid >> 3) & 3)) * 8;
    const __hip_bfloat16* Ab = A  + (size_t)(row0 + (tid >> 2)) * K + ssw;
    const __hip_bfloat16* Bb = Bt + (size_t)(col0 + (tid >> 2)) * K + ssw;
    const int nt = K >> 6;
    const int mbase = wr * (MI * 16);

#pragma unroll
    for (int mi = 0; mi < MI; ++mi)
#pragma unroll
        for (int j = 0; j < 4; ++j) acc[mi][j] = (f32x4){0.f, 0.f, 0.f, 0.f};

    // prologue: 7 slices in stream order
    stage_slice<2>  (Ab +  0, K, &Asl[0][0][0], tid);   // t0.A kh0
    stage_slice<NLB>(Bb +  0, K, &Bsl[0][0][0], tid);   // t0.B kh0
    stage_slice<2>  (Ab + 32, K, &Asl[0][1][0], tid);   // t0.A kh1
    stage_slice<NLB>(Bb + 32, K, &Bsl[0][1][0], tid);   // t0.B kh1
    stage_slice<2>  (Ab + 64, K, &Asl[1][0][0], tid);   // t1.A kh0
    stage_slice<NLB>(Bb + 64, K, &Bsl[1][0][0], tid);   // t1.B kh0
    stage_slice<2>  (Ab + 96, K, &Asl[1][1][0], tid);   // t1.A kh1

    for (int t = 0; t < nt; t += 2) {
#pragma unroll
        for (int pp = 0; pp < 2; ++pp) {
            const int tt  = t + pp;
            const int t1c = (tt + 1 < nt) ? tt + 1 : nt - 1;  // clamped (tail
            const int t2c = (tt + 2 < nt) ? tt + 2 : nt - 1;  // stages land in
                                                              // dead buffers)
            bf16x8 af[MI], bfx[2], bfy[2];

            // ---------- phase 0: kh0, n-frags 0-1
            __builtin_amdgcn_s_waitcnt(WVM);
            __builtin_amdgcn_sched_barrier(0);
#pragma unroll
            for (int mi = 0; mi < MI; ++mi)
                af[mi] = *(const bf16x8*)&Asl[pp][0][(mbase + mi * 16 + ln15) * 32 + rcol];
#pragma unroll
            for (int j = 0; j < 2; ++j)
                bfx[j] = *(const bf16x8*)&Bsl[pp][0][(wc * 64 + j * 16 + ln15) * 32 + rcol];
            stage_slice<NLB>(Bb + (size_t)t1c * 64 + 32, K, &Bsl[pp ^ 1][1][0], tid);
            __builtin_amdgcn_s_barrier();
            __builtin_amdgcn_s_setprio(1);
#pragma unroll
            for (int mi = 0; mi < MI; ++mi)
#pragma unroll
                for (int j = 0; j < 2; ++j)
                    acc[mi][j] = __builtin_amdgcn_mfma_f32_16x16x32_bf16(
                        af[mi], bfx[j], acc[mi][j], 0, 0, 0);
            __builtin_amdgcn_s_setprio(0);
            __builtin_amdgcn_s_barrier();

            // ---------- phase 1: kh0, n-frags 2-3
#pragma unroll
            for (int j = 0; j < 2; ++j)
                bfy[j] = *(const bf16x8*)&Bsl[pp][0][(wc * 64 + (2 + j) * 16 + ln15) * 32 + rcol];
            stage_slice<2>(Ab + (size_t)t2c * 64, K, &Asl[pp][0][0], tid);
            __builtin_amdgcn_s_barrier();
            __builtin_amdgcn_s_setprio(1);
#pragma unroll
            for (int mi = 0; mi < MI; ++mi)
#pragma unroll
                for (int j = 0; j < 2; ++j)
                    acc[mi][2 + j] = __builtin_amdgcn_mfma_f32_16x16x32_bf16(
                        af[mi], bfy[j], acc[mi][2 + j], 0, 0, 0);
            __builtin_amdgcn_s_setprio(0);
            __builtin_amdgcn_s_barrier();

            // ---------- phase 2: kh1, n-frags 0-1
            __builtin_amdgcn_s_waitcnt(WVM);
            __builtin_amdgcn_sched_barrier(0);
#pragma unroll
            for (int mi = 0; mi < MI; ++mi)
                af[mi] = *(const bf16x8*)&Asl[pp][1][(mbase + mi * 16 + ln15) * 32 + rcol];
#pragma unroll
            for (int j = 0; j < 2; ++j)
                bfx[j] = *(const bf16x8*)&Bsl[pp][1][(wc * 64 + j * 16 + ln15) * 32 + rcol];
            stage_slice<NLB>(Bb + (size_t)t2c * 64, K, &Bsl[pp][0][0], tid);
            __builtin_amdgcn_s_barrier();
            __builtin_amdgcn_s_setprio(1);
#pragma unroll
            for (int mi = 0; mi < MI; ++mi)
#pragma unroll
                for (int j = 0; j < 2; ++j)
                    acc[mi][j] = __builtin_amdgcn_mfma_f32_16x16x32_bf16(
                        af[mi], bfx[j], acc[mi][j], 0, 0, 0);
            __builtin_amdgcn_s_setprio(0);
            __builtin_amdgcn_s_barrier();

            // ---------- phase 3: kh1, n-frags 2-3
#pragma unroll
            for (int j = 0; j < 2; ++j)
                bfy[j] = *(const bf16x8*)&Bsl[pp][1][(wc * 64 + (2 + j) * 16 + ln15) * 32 + rcol];
            stage_slice<2>(Ab + (size_t)t2c * 64 + 32, K, &Asl[pp][1][0], tid);
            __builtin_amdgcn_s_barrier();
            __builtin_amdgcn_s_setprio(1);
#pragma unroll
            for (int mi = 0; mi < MI; ++mi)
#pragma unroll
                for (int j = 0; j < 2; ++j)
                    acc[mi][2 + j] = __builtin_amdgcn_mfma_f32_16x16x32_bf16(
                        af[mi], bfy[j], acc[mi][2 + j], 0, 0, 0);
            __builtin_amdgcn_s_setprio(0);
            __builtin_amdgcn_s_barrier();
        }
    }
}

// ---------------- generic 256xBN kernel (bias / gelu / residual / dtype)
template<int WN>
__global__ __launch_bounds__(512) void gemm8_kernel(
    const __hip_bfloat16* __restrict__ A,   // [M,K]
    const __hip_bfloat16* __restrict__ Bt,  // [N,K]
    const float* __restrict__ bias,         // [N]
    const float* __restrict__ residual,     // [M,N] or null
    void* __restrict__ Cout,                // [M,N] fp32 or bf16
    int M, int N, int K, int act, int outBf16)
{
    constexpr int MI = 2 * WN;
    const int row0 = blockIdx.y * 256;
    const int col0 = blockIdx.x * (WN * 64);

    f32x4 acc[MI][4];
    gemm8_core<WN>(A, Bt, K, row0, col0, acc);

    const int tid  = threadIdx.x;
    const int wv   = tid >> 6;
    const int lane = tid & 63;
    const int ln15 = lane & 15;
    const int lq   = lane >> 4;
    const int wr   = wv / WN;
    const int wc   = wv % WN;
    const int mbase = wr * (MI * 16);

#pragma unroll
    for (int mi = 0; mi < MI; ++mi) {
#pragma unroll
        for (int ni = 0; ni < 4; ++ni) {
            const int gc = col0 + wc * 64 + ni * 16 + ln15;
            const float bv = bias[gc];
#pragma unroll
            for (int r = 0; r < 4; ++r) {
                const int gr = row0 + mbase + mi * 16 + lq * 4 + r;
                float v = acc[mi][ni][r] + bv;
                if (act == 1) v = gelu_exact(v);
                if (residual) v += residual[(size_t)gr * N + gc];
                if (outBf16)
                    ((__hip_bfloat16*)Cout)[(size_t)gr * N + gc] = __float2bfloat16(v);
                else
                    ((float*)Cout)[(size_t)gr * N + gc] = v;
            }
        }
    }
}

// ---------------- qkv kernel (WN=4) with routing epilogue
__global__ __launch_bounds__(512) void mfma_qkv8_kernel(
    const __hip_bfloat16* __restrict__ A,
    const __hip_bfloat16* __restrict__ Bt,
    const float* __restrict__ bias,
    __hip_bfloat16* __restrict__ Qb,
    __hip_bfloat16* __restrict__ Kb,
    __hip_bfloat16* __restrict__ Vtb)
{
    const int row0 = blockIdx.y * 256;
    const int col0 = blockIdx.x * 256;

    f32x4 acc[8][4];
    gemm8_core<4>(A, Bt, D_MODEL, row0, col0, acc);

    const int tid  = threadIdx.x;
    const int wv   = tid >> 6;
    const int lane = tid & 63;
    const int ln15 = lane & 15;
    const int lq   = lane >> 4;
    const int wr   = wv >> 2;
    const int wc   = wv & 3;

#pragma unroll
    for (int mi = 0; mi < 8; ++mi) {
        const int gr0 = row0 + wr * 128 + mi * 16 + lq * 4;   // + r
        const int bb  = gr0 >> 11;
        const int q0  = gr0 & 2047;
#pragma unroll
        for (int ni = 0; ni < 4; ++ni) {
            const int gc  = col0 + wc * 64 + ni * 16 + ln15;
            const float bv = bias[gc];
            const int sec = gc >> 10;            // 0:Q 1:K 2:V
            const int hd  = (gc & 1023) >> 6;
            const int d   = gc & 63;
            if (sec == 2) {
                unsigned short u[4];
#pragma unroll
                for (int r = 0; r < 4; ++r) {
                    __hip_bfloat16 e = __float2bfloat16(acc[mi][ni][r] + bv);
                    u[r] = *(unsigned short*)&e;
                }
                uint2 pk;
                pk.x = (unsigned int)u[0] | ((unsigned int)u[1] << 16);
                pk.y = (unsigned int)u[2] | ((unsigned int)u[3] << 16);
                *(uint2*)(Vtb + ((size_t)((bb * N_HEAD + hd) * D_HEAD + d)) * SEQ_T + q0) = pk;
            } else {
                __hip_bfloat16* dst = (sec == 0 ? Qb : Kb)
                    + ((size_t)((bb * N_HEAD + hd) * SEQ_T + q0)) * D_HEAD + d;
#pragma unroll
                for (int r = 0; r < 4; ++r)
                    dst[(size_t)r * D_HEAD] = __float2bfloat16(acc[mi][ni][r] + bv);
            }
        }
    }
}

// ------------------------------------------------- MFMA flash attention v4
// (unchanged from Round 11)
#define ATQ 64
#define ATK 128
#define NQT (SEQ_T / ATQ)   // 32
#define KP  72              // Ks row stride (elems)
#define VP  136             // Vts row stride (elems)

__global__ __launch_bounds__(256) void mfma_attn_kernel(
    const __hip_bfloat16* __restrict__ Qb,
    const __hip_bfloat16* __restrict__ Kb,
    const __hip_bfloat16* __restrict__ Vtb,
    __hip_bfloat16* __restrict__ y)
{
    __shared__ __align__(16) __hip_bfloat16 Ks[ATK * KP];      // [j][d]; O-scratch in epilogue
    __shared__ __align__(16) __hip_bfloat16 Vts[D_HEAD * VP];  // [d][j]

    const int pair = blockIdx.x;   // 0..15
    const int h    = blockIdx.y;
    const int b    = blockIdx.z;
    const int tid  = threadIdx.x;
    const int wv   = tid >> 6;
    const int lane = tid & 63;
    const int ln15 = lane & 15;
    const int lq   = lane >> 4;

    const __hip_bfloat16* Qh = Qb  + (size_t)(b * N_HEAD + h) * SEQ_T * D_HEAD;
    const __hip_bfloat16* Kh = Kb  + (size_t)(b * N_HEAD + h) * SEQ_T * D_HEAD;
    const __hip_bfloat16* Vh = Vtb + (size_t)(b * N_HEAD + h) * D_HEAD * SEQ_T;
    const size_t bT = (size_t)b * SEQ_T;

    const float CEXP = 0.18033688011f;   // 0.125 * log2(e)

#pragma unroll 1
    for (int half = 0; half < 2; ++half) {
        const int qt    = half == 0 ? pair : (NQT - 1 - pair);
        const int qbase = qt * ATQ;
        const int ntk   = (qt >> 1) + 1;
        const int qg    = qbase + wv * 16 + ln15;   // stats-owner q row

        bf16x8 qf[2];
#pragma unroll
        for (int kc = 0; kc < 2; ++kc)
            qf[kc] = *(const bf16x8*)(Qh + (size_t)(qbase + wv * 16 + ln15) * D_HEAD
                                      + kc * 32 + lq * 8);

        f32x4 Oacc[4];
#pragma unroll
        for (int dn = 0; dn < 4; ++dn) Oacc[dn] = (f32x4){0.f, 0.f, 0.f, 0.f};
        float m_run = -INFINITY, l_run = 0.f;

        for (int t = 0; t < ntk; ++t) {
            const int kb = t * ATK;
            __syncthreads();   // prev iter's LDS reads (and prev-half epilogue) done
            // stage K tile [128][64]
#pragma unroll
            for (int i = 0; i < 4; ++i) {
                const int ch = tid + i * 256;
                const int r = ch >> 3, c8 = (ch & 7) * 8;
                *(bf16x8*)&Ks[r * KP + c8] =
                    *(const bf16x8*)(Kh + (size_t)(kb + r) * D_HEAD + c8);
            }
            // stage Vt tile [64][128]
#pragma unroll
            for (int i = 0; i < 4; ++i) {
                const int ch = tid + i * 256;
                const int r = ch >> 4, c8 = (ch & 15) * 8;
                *(bf16x8*)&Vts[r * VP + c8] =
                    *(const bf16x8*)(Vh + (size_t)r * SEQ_T + kb + c8);
            }
            __syncthreads();

            // ---- S^T[j=128][q=16] : A=K (rows j), B=Q (rows q), 16x16x32
            f32x4 st[8];
#pragma unroll
            for (int jf = 0; jf < 8; ++jf) st[jf] = (f32x4){0.f, 0.f, 0.f, 0.f};
#pragma unroll
            for (int jf = 0; jf < 8; ++jf) {
                const bf16x8 kf0 = *(const bf16x8*)&Ks[(jf * 16 + ln15) * KP + lq * 8];
                const bf16x8 kf1 = *(const bf16x8*)&Ks[(jf * 16 + ln15) * KP + 32 + lq * 8];
                st[jf] = __builtin_amdgcn_mfma_f32_16x16x32_bf16(kf0, qf[0], st[jf], 0, 0, 0);
                st[jf] = __builtin_amdgcn_mfma_f32_16x16x32_bf16(kf1, qf[1], st[jf], 0, 0, 0);
            }

            // ---- causal mask on the diagonal tile (raw-score domain)
            if (t == ntk - 1) {
#pragma unroll
                for (int jf = 0; jf < 8; ++jf)
#pragma unroll
                    for (int r = 0; r < 4; ++r)
                        if ((kb + jf * 16 + lq * 4 + r) > qg) st[jf][r] = -INFINITY;
            }

            // ---- online softmax for q=qg (raw max; exp2 with folded scale)
            float tmax = st[0][0];
#pragma unroll
            for (int jf = 0; jf < 8; ++jf)
#pragma unroll
                for (int r = 0; r < 4; ++r) tmax = fmaxf(tmax, st[jf][r]);
            tmax = fmaxf(tmax, __shfl_xor(tmax, 16));
            tmax = fmaxf(tmax, __shfl_xor(tmax, 32));
            const float mnew  = fmaxf(m_run, tmax);
            const float alpha = exp2f((m_run - mnew) * CEXP);
            const float mc    = mnew * CEXP;
            float psum = 0.f;
#pragma unroll
            for (int jf = 0; jf < 8; ++jf)
#pragma unroll
                for (int r = 0; r < 4; ++r) {
                    const float p = exp2f(fmaf(st[jf][r], CEXP, -mc));
                    st[jf][r] = p;
                    psum += p;
                }
            psum += __shfl_xor(psum, 16);
            psum += __shfl_xor(psum, 32);
            l_run = alpha * l_run + psum;
            m_run = mnew;

            float a4[4];
#pragma unroll
            for (int r = 0; r < 4; ++r) a4[r] = __shfl(alpha, lq * 4 + r);
#pragma unroll
            for (int dn = 0; dn < 4; ++dn)
#pragma unroll
                for (int r = 0; r < 4; ++r) Oacc[dn][r] *= a4[r];

            // ---- O += P V via 16x16x16: P-frag is the S^T C-fragment
#pragma unroll
            for (int jf = 0; jf < 8; ++jf) {
                s16x4 pfr;
#pragma unroll
                for (int s = 0; s < 4; ++s) {
                    __hip_bfloat16 e = __float2bfloat16(st[jf][s]);
                    pfr[s] = __builtin_bit_cast(short, e);
                }
#pragma unroll
                for (int dn = 0; dn < 4; ++dn) {
                    const s16x4 vfr = *(const s16x4*)&Vts[(dn * 16 + ln15) * VP
                                                          + jf * 16 + lq * 4];
                    Oacc[dn] = mfma16_bf16(pfr, vfr, Oacc[dn]);
                }
            }
        }

        // ---- epilogue: transpose O through Ks (barrier: Ks reuse after reads)
        __syncthreads();
        float il[4];
#pragma unroll
        for (int r = 0; r < 4; ++r) il[r] = 1.0f / __shfl(l_run, lq * 4 + r);
#pragma unroll
        for (int dn = 0; dn < 4; ++dn)
#pragma unroll
            for (int r = 0; r < 4; ++r)
                Ks[(wv * 16 + lq * 4 + r) * 72 + dn * 16 + ln15] =
                    __float2bfloat16(Oacc[dn][r] * il[r]);
        const int r2 = lane >> 3, c8 = (lane & 7) * 8;
#pragma unroll
        for (int i = 0; i < 2; ++i) {
            const int row = wv * 16 + r2 + 8 * i;
            const bf16x8 val = *(const bf16x8*)&Ks[row * 72 + c8];
            *(bf16x8*)(y + (bT + qbase + row) * D_MODEL + h * D_HEAD + c8) = val;
        }
    }
}

// ------------------------------------------------------------------ launch
extern "C" void kernel_launch(void* const* d_in, const int* in_sizes, int n_in,
                              void* d_out, int out_size, void* d_ws, size_t ws_size,
                              hipStream_t stream)
{
    const float* x      = (const float*)d_in[0];
    const float* ln1_w  = (const float*)d_in[1];
    const float* ln1_b  = (const float*)d_in[2];
    const float* attn_w = (const float*)d_in[3];
    const float* attn_b = (const float*)d_in[4];
    const float* proj_w = (const float*)d_in[5];
    const float* proj_b = (const float*)d_in[6];
    const float* ln2_w  = (const float*)d_in[7];
    const float* ln2_b  = (const float*)d_in[8];
    const float* fc_w   = (const float*)d_in[9];
    const float* fc_b   = (const float*)d_in[10];
    const float* fc2_w  = (const float*)d_in[11];
    const float* fc2_b  = (const float*)d_in[12];
    float* out = (float*)d_out;

    char* ws = (char*)d_ws;
    __hip_bfloat16* Qb      = (__hip_bfloat16*)(ws);
    __hip_bfloat16* Kb      = (__hip_bfloat16*)(ws + (size_t)8  * 1024 * 1024);
    __hip_bfloat16* Vtb     = (__hip_bfloat16*)(ws + (size_t)16 * 1024 * 1024);
    __hip_bfloat16* h_bf    = (__hip_bfloat16*)(ws);
    __hip_bfloat16* ln_buf  = (__hip_bfloat16*)(ws + (size_t)32 * 1024 * 1024);
    __hip_bfloat16* y_buf   = (__hip_bfloat16*)(ws + (size_t)40 * 1024 * 1024);
    float*          xmid    = (float*)(ws + (size_t)48 * 1024 * 1024);
    __hip_bfloat16* attn_wt = (__hip_bfloat16*)(ws + (size_t)64 * 1024 * 1024);
    __hip_bfloat16* proj_wt = (__hip_bfloat16*)(ws + (size_t)70 * 1024 * 1024);
    __hip_bfloat16* fc_wt   = (__hip_bfloat16*)(ws + (size_t)72 * 1024 * 1024);
    __hip_bfloat16* fc2_wt  = (__hip_bfloat16*)(ws + (size_t)80 * 1024 * 1024);

    dim3 blk256(256);
    dim3 blk512(512);

    // 0. all weight transposes in one launch (fp32 [K,N] -> bf16 [N,K])
    transpose_all_kernel<<<dim3(12288), blk256, 0, stream>>>(
        attn_w, proj_w, fc_w, fc2_w, attn_wt, proj_wt, fc_wt, fc2_wt);

    // 1. ln1(x) -> ln_buf (bf16)
    ln_kernel<<<dim3(NROWS), blk256, 0, stream>>>(x, ln1_w, ln1_b, ln_buf, D_MODEL);

    // 2. qkv GEMM (8-phase 256x256) -> Qb/Kb/Vtb
    mfma_qkv8_kernel<<<dim3(C3 / 256, NROWS / 256), blk512, 0, stream>>>(
        ln_buf, attn_wt, attn_b, Qb, Kb, Vtb);

    // 3. MFMA flash attention v4 -> y_buf (bf16)
    mfma_attn_kernel<<<dim3(NQT / 2, N_HEAD, BATCH), blk256, 0, stream>>>(
        Qb, Kb, Vtb, y_buf);

    // 4. xmid = x + y_buf @ proj_w + proj_b  (fp32, 8-phase 256x128)
    gemm8_kernel<2><<<dim3(D_MODEL / 128, NROWS / 256), blk512, 0, stream>>>(
        y_buf, proj_wt, proj_b, x, xmid, NROWS, D_MODEL, D_MODEL, 0, 0);

    // 5. ln2(xmid) -> ln_buf (bf16)
    ln_kernel<<<dim3(NROWS), blk256, 0, stream>>>(xmid, ln2_w, ln2_b, ln_buf, D_MODEL);

    // 6. h = gelu(ln_buf @ fc_w + fc_b) -> bf16 (8-phase 256x256)
    gemm8_kernel<4><<<dim3(D_FF / 256, NROWS / 256), blk512, 0, stream>>>(
        ln_buf, fc_wt, fc_b, nullptr, h_bf, NROWS, D_FF, D_MODEL, 1, 1);

    // 7. out = xmid + h @ fc2_w + fc2_b  (fp32, 8-phase 256x128)
    gemm8_kernel<2><<<dim3(D_MODEL / 128, NROWS / 256), blk512, 0, stream>>>(
        h_bf, fc2_wt, fc2_b, xmid, out, NROWS, D_MODEL, D_FF, 0, 0);
}

// Round 3
// 403.881 us; speedup vs baseline: 1.4090x; 1.4090x over previous
//
#include <hip/hip_runtime.h>
#include <hip/hip_bf16.h>
#include <math.h>

// Transformer block. Round 14: rot4 GEMM cores with RACE-FIXED wait order.
// R13's per-tile vmcnt wait sat before the same-phase ds_reads -> cross-wave
// race (my wait drains MY loads; rows I read were staged by OTHER waves).
// Fix per m201: drain -> barrier -> read. The single WAIT_VM8 per tile now
// sits after the tile's last stage, before the pre-MFMA barrier; the data it
// drains (tile t+1) is first read 2 barriers later. Prologue gains
// WAIT+barrier. Everything else as R13: BK=32 4-slot rotation, 3-tile lead,
// no sched_barrier (m141), setprio around MFMA (T5), granule swizzle with
// 0 measured conflicts (T2, both-sides per rule #21), XCD swizzle (T1).
// D_MODEL=1024, N_HEAD=16, D_HEAD=64, EXP=4, B=2, T=2048, EPS=1e-5

#define D_MODEL 1024
#define N_HEAD  16
#define D_HEAD  64
#define SEQ_T   2048
#define BATCH   2
#define NROWS   (BATCH * SEQ_T)   // 4096
#define C3      (3 * D_MODEL)     // 3072
#define D_FF    (4 * D_MODEL)     // 4096

typedef __bf16 bf16x8 __attribute__((ext_vector_type(8)));
typedef __bf16 bf16x4t __attribute__((ext_vector_type(4)));
typedef short  s16x4  __attribute__((ext_vector_type(4)));
typedef float  f32x4  __attribute__((ext_vector_type(4)));

// one wait per K-tile: drains the 4 loads of tile t+1 (issued 2 tiles ago),
// leaves 8 outstanding (tiles t+2, t+3). Never 0 in the loop (T4).
// Followed by a barrier before anyone reads the drained data (race-free).
#define WAIT_VM8() asm volatile("s_waitcnt vmcnt(8)" ::: "memory")

// 16x16x16 bf16 MFMA: builtin name differs across ROCm versions.
__device__ __forceinline__ f32x4 mfma16_bf16(s16x4 a, s16x4 b, f32x4 c)
{
#if __has_builtin(__builtin_amdgcn_mfma_f32_16x16x16_bf16)
    return __builtin_amdgcn_mfma_f32_16x16x16_bf16(
        __builtin_bit_cast(bf16x4t, a), __builtin_bit_cast(bf16x4t, b), c, 0, 0, 0);
#else
    return __builtin_amdgcn_mfma_f32_16x16x16bf16_1k(a, b, c, 0, 0, 0);
#endif
}

// ---------------------------------------------------------------- LayerNorm
__global__ __launch_bounds__(256) void ln_kernel(
    const float* __restrict__ in, const float* __restrict__ w,
    const float* __restrict__ b, __hip_bfloat16* __restrict__ out, int D)
{
    const int row = blockIdx.x;
    const int tid = threadIdx.x;
    const float* x = in + (size_t)row * D;

    float s = 0.f, s2 = 0.f;
    for (int i = tid; i < D; i += 256) {
        float v = x[i];
        s += v; s2 += v * v;
    }
    __shared__ float rs[256], rs2[256];
    rs[tid] = s; rs2[tid] = s2;
    __syncthreads();
    for (int off = 128; off > 0; off >>= 1) {
        if (tid < off) { rs[tid] += rs[tid + off]; rs2[tid] += rs2[tid + off]; }
        __syncthreads();
    }
    const float mu   = rs[0] / D;
    const float var  = rs2[0] / D - mu * mu;
    const float rstd = rsqrtf(var + 1e-5f);

    __hip_bfloat16* o = out + (size_t)row * D;
    for (int i = tid; i < D; i += 256)
        o[i] = __float2bfloat16((x[i] - mu) * rstd * w[i] + b[i]);
}

// -------------------------------- merged weight transpose + bf16 cast (x4)
__global__ __launch_bounds__(256) void transpose_all_kernel(
    const float* __restrict__ attn_w, const float* __restrict__ proj_w,
    const float* __restrict__ fc_w,   const float* __restrict__ fc2_w,
    __hip_bfloat16* __restrict__ attn_wt, __hip_bfloat16* __restrict__ proj_wt,
    __hip_bfloat16* __restrict__ fc_wt,   __hip_bfloat16* __restrict__ fc2_wt)
{
    __shared__ float t[32][33];
    int tb = blockIdx.x;
    const float* W; __hip_bfloat16* Wt; int K, N;
    if (tb < 3072)      { W = attn_w; Wt = attn_wt; K = D_MODEL; N = C3; }
    else if (tb < 4096) { tb -= 3072; W = proj_w; Wt = proj_wt; K = D_MODEL; N = D_MODEL; }
    else if (tb < 8192) { tb -= 4096; W = fc_w;   Wt = fc_wt;   K = D_MODEL; N = D_FF; }
    else                { tb -= 8192; W = fc2_w;  Wt = fc2_wt;  K = D_FF;    N = D_MODEL; }
    const int ntx = N >> 5;
    const int k0 = (tb / ntx) * 32;
    const int n0 = (tb % ntx) * 32;

    const int tx = threadIdx.x & 31;
    const int ty = threadIdx.x >> 5;
#pragma unroll
    for (int i = 0; i < 4; ++i)
        t[ty + 8 * i][tx] = W[(size_t)(k0 + ty + 8 * i) * N + n0 + tx];
    __syncthreads();
#pragma unroll
    for (int i = 0; i < 4; ++i)
        Wt[(size_t)(n0 + ty + 8 * i) * K + k0 + tx] =
            __float2bfloat16(t[tx][ty + 8 * i]);
}

// ----------------------------------------------------------- helpers
__device__ __forceinline__ void async16(const __hip_bfloat16* g, __hip_bfloat16* l)
{
    __builtin_amdgcn_global_load_lds(
        (const __attribute__((address_space(1))) void*)g,
        (__attribute__((address_space(3))) void*)l, 16, 0, 0);
}

__device__ __forceinline__ float gelu_exact(float v)
{
    return 0.5f * v * (1.0f + erff(v * 0.70710678118654752f));
}

// XCD-contiguous work remap (T1). All GEMM grids here are %8 == 0.
__device__ __forceinline__ void swz_xcd(int& bx, int& by)
{
    const int nbx = gridDim.x;
    const int nwg = nbx * gridDim.y;
    int lin = blockIdx.y * nbx + blockIdx.x;
    const int per = nwg >> 3;
    lin = (lin & 7) * per + (lin >> 3);   // XCD x -> contiguous work chunk
    bx = lin % nbx;
    by = lin / nbx;
}

// ================== rot4 GEMM cores (BK=32, 4-slot rotation) ==============
// Slice = [rows][32] bf16, 64B rows. Granule swizzle (T2, both-sides):
// LDS dst granule g holds source granule g ^ ((row>>1)&3); reader at
// (row, k-granule lq) reads granule lq ^ ((row>>1)&3). 0 conflicts (R12).
// Schedule per K-tile t (slot sl = t&3):
//   ds_read fragments from slot sl      (drained+barrier'd at tile t-1)
//   stage slices of tile min(t+3,nt-1) into slot (t+3)&3
//     (that slot's data, tile t-1, was last read before the previous
//      post-MFMA barrier -> WAR-safe)
//   WAIT_VM8  (drains tile t+1's 4 loads; 8 stay in flight)
//   barrier; setprio(1); MFMA; setprio(0); barrier
// Reads of tile t+1 happen 2 barriers after every wave's drain: race-free.
// Tail: dummy re-stages of tile nt-1 land in provably dead slots, keeping
// the vmcnt ledger uniform.

template<int NL, int TPB>
__device__ __forceinline__ void stage_slice(
    const __hip_bfloat16* __restrict__ g, int K,
    __hip_bfloat16* __restrict__ ldst, int tid)
{
#pragma unroll
    for (int i = 0; i < NL; ++i)
        async16(g + (size_t)(i * (TPB / 4)) * K, ldst + i * (TPB / 4) * 32 + tid * 8);
}

// ---------------- 256x256 core, 512 threads, 8 waves (2M x 4N), 128KB LDS
__device__ __forceinline__ void gemm_rot4_512(
    const __hip_bfloat16* __restrict__ A,
    const __hip_bfloat16* __restrict__ Bt,
    int K, int row0, int col0, f32x4 (&acc)[8][4])
{
    __shared__ __align__(16) __hip_bfloat16 Asl[4][256 * 32];
    __shared__ __align__(16) __hip_bfloat16 Bsl[4][256 * 32];

    const int tid  = threadIdx.x;
    const int wv   = tid >> 6;
    const int lane = tid & 63;
    const int ln15 = lane & 15;
    const int lq   = lane >> 4;
    const int mbase = (wv >> 2) * 128;
    const int nbase = (wv & 3) * 64;
    const int rcol = (lq ^ ((ln15 >> 1) & 3)) * 8;
    const int ssw  = ((tid & 3) ^ ((tid >> 3) & 3)) * 8;
    const __hip_bfloat16* Ab = A  + (size_t)(row0 + (tid >> 2)) * K + ssw;
    const __hip_bfloat16* Bb = Bt + (size_t)(col0 + (tid >> 2)) * K + ssw;
    const int nt = K >> 5;   // K-tiles of 32; callers pass K % 128 == 0

#pragma unroll
    for (int mi = 0; mi < 8; ++mi)
#pragma unroll
        for (int ni = 0; ni < 4; ++ni) acc[mi][ni] = (f32x4){0.f, 0.f, 0.f, 0.f};

    // prologue: tiles 0,1,2 -> slots 0,1,2 (12 loads/wave); drain tile 0,
    // then barrier so EVERY wave's tile-0 loads have landed before reads.
#pragma unroll
    for (int t = 0; t < 3; ++t) {
        stage_slice<2, 512>(Ab + t * 32, K, &Asl[t][0], tid);
        stage_slice<2, 512>(Bb + t * 32, K, &Bsl[t][0], tid);
    }
    WAIT_VM8();
    __builtin_amdgcn_s_barrier();

    for (int tq = 0; tq < nt; tq += 4) {
#pragma unroll
        for (int u = 0; u < 4; ++u) {
            const int t   = tq + u;
            const int tcl = (t + 3 < nt) ? t + 3 : nt - 1;
            const int sl  = u;             // t & 3
            const int sl3 = (u + 3) & 3;   // (t+3) & 3
            bf16x8 af[4], bfr[4];

            // ---- phase 0: m-frags 0-3 (rows mbase..mbase+63)
#pragma unroll
            for (int mi = 0; mi < 4; ++mi)
                af[mi] = *(const bf16x8*)&Asl[sl][(mbase + mi * 16 + ln15) * 32 + rcol];
#pragma unroll
            for (int ni = 0; ni < 4; ++ni)
                bfr[ni] = *(const bf16x8*)&Bsl[sl][(nbase + ni * 16 + ln15) * 32 + rcol];
            stage_slice<2, 512>(Ab + (size_t)tcl * 32, K, &Asl[sl3][0], tid);
            __builtin_amdgcn_s_barrier();
            __builtin_amdgcn_s_setprio(1);
#pragma unroll
            for (int mi = 0; mi < 4; ++mi)
#pragma unroll
                for (int ni = 0; ni < 4; ++ni)
                    acc[mi][ni] = __builtin_amdgcn_mfma_f32_16x16x32_bf16(
                        af[mi], bfr[ni], acc[mi][ni], 0, 0, 0);
            __builtin_amdgcn_s_setprio(0);
            __builtin_amdgcn_s_barrier();

            // ---- phase 1: m-frags 4-7 (rows mbase+64..mbase+127)
#pragma unroll
            for (int mi = 0; mi < 4; ++mi)
                af[mi] = *(const bf16x8*)&Asl[sl][(mbase + 64 + mi * 16 + ln15) * 32 + rcol];
            stage_slice<2, 512>(Bb + (size_t)tcl * 32, K, &Bsl[sl3][0], tid);
            WAIT_VM8();                    // drain tile t+1 BEFORE barrier
            __builtin_amdgcn_s_barrier();
            __builtin_amdgcn_s_setprio(1);
#pragma unroll
            for (int mi = 0; mi < 4; ++mi)
#pragma unroll
                for (int ni = 0; ni < 4; ++ni)
                    acc[4 + mi][ni] = __builtin_amdgcn_mfma_f32_16x16x32_bf16(
                        af[mi], bfr[ni], acc[4 + mi][ni], 0, 0, 0);
            __builtin_amdgcn_s_setprio(0);
            __builtin_amdgcn_s_barrier();
        }
    }
}

// ---------------- 128x128 core, 256 threads, 4 waves (2M x 2N), 64KB LDS
__device__ __forceinline__ void gemm_rot4_256(
    const __hip_bfloat16* __restrict__ A,
    const __hip_bfloat16* __restrict__ Bt,
    int K, int row0, int col0, f32x4 (&acc)[4][4])
{
    __shared__ __align__(16) __hip_bfloat16 Asl[4][128 * 32];
    __shared__ __align__(16) __hip_bfloat16 Bsl[4][128 * 32];

    const int tid  = threadIdx.x;
    const int wv   = tid >> 6;
    const int lane = tid & 63;
    const int ln15 = lane & 15;
    const int lq   = lane >> 4;
    const int mbase = (wv >> 1) * 64;
    const int nbase = (wv & 1) * 64;
    const int rcol = (lq ^ ((ln15 >> 1) & 3)) * 8;
    const int ssw  = ((tid & 3) ^ ((tid >> 3) & 3)) * 8;
    const __hip_bfloat16* Ab = A  + (size_t)(row0 + (tid >> 2)) * K + ssw;
    const __hip_bfloat16* Bb = Bt + (size_t)(col0 + (tid >> 2)) * K + ssw;
    const int nt = K >> 5;

#pragma unroll
    for (int mi = 0; mi < 4; ++mi)
#pragma unroll
        for (int ni = 0; ni < 4; ++ni) acc[mi][ni] = (f32x4){0.f, 0.f, 0.f, 0.f};

#pragma unroll
    for (int t = 0; t < 3; ++t) {
        stage_slice<2, 256>(Ab + t * 32, K, &Asl[t][0], tid);
        stage_slice<2, 256>(Bb + t * 32, K, &Bsl[t][0], tid);
    }
    WAIT_VM8();
    __builtin_amdgcn_s_barrier();

    for (int tq = 0; tq < nt; tq += 4) {
#pragma unroll
        for (int u = 0; u < 4; ++u) {
            const int t   = tq + u;
            const int tcl = (t + 3 < nt) ? t + 3 : nt - 1;
            const int sl  = u;
            const int sl3 = (u + 3) & 3;
            bf16x8 af[4], bfr[4];

#pragma unroll
            for (int mi = 0; mi < 4; ++mi)
                af[mi] = *(const bf16x8*)&Asl[sl][(mbase + mi * 16 + ln15) * 32 + rcol];
#pragma unroll
            for (int ni = 0; ni < 4; ++ni)
                bfr[ni] = *(const bf16x8*)&Bsl[sl][(nbase + ni * 16 + ln15) * 32 + rcol];
            stage_slice<2, 256>(Ab + (size_t)tcl * 32, K, &Asl[sl3][0], tid);
            stage_slice<2, 256>(Bb + (size_t)tcl * 32, K, &Bsl[sl3][0], tid);
            WAIT_VM8();                    // drain tile t+1 BEFORE barrier
            __builtin_amdgcn_s_barrier();
            __builtin_amdgcn_s_setprio(1);
#pragma unroll
            for (int mi = 0; mi < 4; ++mi)
#pragma unroll
                for (int ni = 0; ni < 4; ++ni)
                    acc[mi][ni] = __builtin_amdgcn_mfma_f32_16x16x32_bf16(
                        af[mi], bfr[ni], acc[mi][ni], 0, 0, 0);
            __builtin_amdgcn_s_setprio(0);
            __builtin_amdgcn_s_barrier();
        }
    }
}

// ---------------- 256x256 kernel (fc1)
__global__ __launch_bounds__(512) void gemm256_kernel(
    const __hip_bfloat16* __restrict__ A,   // [M,K]
    const __hip_bfloat16* __restrict__ Bt,  // [N,K]
    const float* __restrict__ bias,         // [N]
    const float* __restrict__ residual,     // [M,N] or null
    void* __restrict__ Cout,                // [M,N] fp32 or bf16
    int M, int N, int K, int act, int outBf16)
{
    int bx, by;
    swz_xcd(bx, by);
    const int row0 = by * 256;
    const int col0 = bx * 256;

    f32x4 acc[8][4];
    gemm_rot4_512(A, Bt, K, row0, col0, acc);

    const int tid  = threadIdx.x;
    const int wv   = tid >> 6;
    const int lane = tid & 63;
    const int ln15 = lane & 15;
    const int lq   = lane >> 4;
    const int mbase = (wv >> 2) * 128;
    const int nbase = (wv & 3) * 64;

#pragma unroll
    for (int mi = 0; mi < 8; ++mi) {
#pragma unroll
        for (int ni = 0; ni < 4; ++ni) {
            const int gc = col0 + nbase + ni * 16 + ln15;
            const float bv = bias[gc];
#pragma unroll
            for (int r = 0; r < 4; ++r) {
                const int gr = row0 + mbase + mi * 16 + lq * 4 + r;
                float v = acc[mi][ni][r] + bv;
                if (act == 1) v = gelu_exact(v);
                if (residual) v += residual[(size_t)gr * N + gc];
                if (outBf16)
                    ((__hip_bfloat16*)Cout)[(size_t)gr * N + gc] = __float2bfloat16(v);
                else
                    ((float*)Cout)[(size_t)gr * N + gc] = v;
            }
        }
    }
}

// ---------------- 128x128 kernel (proj, fc2)
__global__ __launch_bounds__(256, 2) void gemm128_kernel(
    const __hip_bfloat16* __restrict__ A,
    const __hip_bfloat16* __restrict__ Bt,
    const float* __restrict__ bias,
    const float* __restrict__ residual,
    void* __restrict__ Cout,
    int M, int N, int K, int act, int outBf16)
{
    int bx, by;
    swz_xcd(bx, by);
    const int row0 = by * 128;
    const int col0 = bx * 128;

    f32x4 acc[4][4];
    gemm_rot4_256(A, Bt, K, row0, col0, acc);

    const int tid  = threadIdx.x;
    const int wv   = tid >> 6;
    const int lane = tid & 63;
    const int ln15 = lane & 15;
    const int lq   = lane >> 4;
    const int mbase = (wv >> 1) * 64;
    const int nbase = (wv & 1) * 64;

#pragma unroll
    for (int mi = 0; mi < 4; ++mi) {
#pragma unroll
        for (int ni = 0; ni < 4; ++ni) {
            const int gc = col0 + nbase + ni * 16 + ln15;
            const float bv = bias[gc];
#pragma unroll
            for (int r = 0; r < 4; ++r) {
                const int gr = row0 + mbase + mi * 16 + lq * 4 + r;
                float v = acc[mi][ni][r] + bv;
                if (act == 1) v = gelu_exact(v);
                if (residual) v += residual[(size_t)gr * N + gc];
                if (outBf16)
                    ((__hip_bfloat16*)Cout)[(size_t)gr * N + gc] = __float2bfloat16(v);
                else
                    ((float*)Cout)[(size_t)gr * N + gc] = v;
            }
        }
    }
}

// ---------------- qkv kernel (256x256 core) with routing epilogue
__global__ __launch_bounds__(512) void qkv256_kernel(
    const __hip_bfloat16* __restrict__ A,
    const __hip_bfloat16* __restrict__ Bt,
    const float* __restrict__ bias,
    __hip_bfloat16* __restrict__ Qb,
    __hip_bfloat16* __restrict__ Kb,
    __hip_bfloat16* __restrict__ Vtb)
{
    int bx, by;
    swz_xcd(bx, by);
    const int row0 = by * 256;
    const int col0 = bx * 256;

    f32x4 acc[8][4];
    gemm_rot4_512(A, Bt, D_MODEL, row0, col0, acc);

    const int tid  = threadIdx.x;
    const int wv   = tid >> 6;
    const int lane = tid & 63;
    const int ln15 = lane & 15;
    const int lq   = lane >> 4;
    const int mbase = (wv >> 2) * 128;
    const int nbase = (wv & 3) * 64;

#pragma unroll
    for (int mi = 0; mi < 8; ++mi) {
        const int gr0 = row0 + mbase + mi * 16 + lq * 4;   // + r
        const int bb  = gr0 >> 11;
        const int q0  = gr0 & 2047;
#pragma unroll
        for (int ni = 0; ni < 4; ++ni) {
            const int gc  = col0 + nbase + ni * 16 + ln15;
            const float bv = bias[gc];
            const int sec = gc >> 10;            // 0:Q 1:K 2:V
            const int hd  = (gc & 1023) >> 6;
            const int d   = gc & 63;
            if (sec == 2) {
                unsigned short u[4];
#pragma unroll
                for (int r = 0; r < 4; ++r) {
                    __hip_bfloat16 e = __float2bfloat16(acc[mi][ni][r] + bv);
                    u[r] = *(unsigned short*)&e;
                }
                uint2 pk;
                pk.x = (unsigned int)u[0] | ((unsigned int)u[1] << 16);
                pk.y = (unsigned int)u[2] | ((unsigned int)u[3] << 16);
                *(uint2*)(Vtb + ((size_t)((bb * N_HEAD + hd) * D_HEAD + d)) * SEQ_T + q0) = pk;
            } else {
                __hip_bfloat16* dst = (sec == 0 ? Qb : Kb)
                    + ((size_t)((bb * N_HEAD + hd) * SEQ_T + q0)) * D_HEAD + d;
#pragma unroll
                for (int r = 0; r < 4; ++r)
                    dst[(size_t)r * D_HEAD] = __float2bfloat16(acc[mi][ni][r] + bv);
            }
        }
    }
}

// ------------------------------------------------- MFMA flash attention v4
// (unchanged from Round 11)
#define ATQ 64
#define ATK 128
#define NQT (SEQ_T / ATQ)   // 32
#define KP  72              // Ks row stride (elems)
#define VP  136             // Vts row stride (elems)

__global__ __launch_bounds__(256) void mfma_attn_kernel(
    const __hip_bfloat16* __restrict__ Qb,
    const __hip_bfloat16* __restrict__ Kb,
    const __hip_bfloat16* __restrict__ Vtb,
    __hip_bfloat16* __restrict__ y)
{
    __shared__ __align__(16) __hip_bfloat16 Ks[ATK * KP];      // [j][d]; O-scratch in epilogue
    __shared__ __align__(16) __hip_bfloat16 Vts[D_HEAD * VP];  // [d][j]

    const int pair = blockIdx.x;   // 0..15
    const int h    = blockIdx.y;
    const int b    = blockIdx.z;
    const int tid  = threadIdx.x;
    const int wv   = tid >> 6;
    const int lane = tid & 63;
    const int ln15 = lane & 15;
    const int lq   = lane >> 4;

    const __hip_bfloat16* Qh = Qb  + (size_t)(b * N_HEAD + h) * SEQ_T * D_HEAD;
    const __hip_bfloat16* Kh = Kb  + (size_t)(b * N_HEAD + h) * SEQ_T * D_HEAD;
    const __hip_bfloat16* Vh = Vtb + (size_t)(b * N_HEAD + h) * D_HEAD * SEQ_T;
    const size_t bT = (size_t)b * SEQ_T;

    const float CEXP = 0.18033688011f;   // 0.125 * log2(e)

#pragma unroll 1
    for (int half = 0; half < 2; ++half) {
        const int qt    = half == 0 ? pair : (NQT - 1 - pair);
        const int qbase = qt * ATQ;
        const int ntk   = (qt >> 1) + 1;
        const int qg    = qbase + wv * 16 + ln15;   // stats-owner q row

        bf16x8 qf[2];
#pragma unroll
        for (int kc = 0; kc < 2; ++kc)
            qf[kc] = *(const bf16x8*)(Qh + (size_t)(qbase + wv * 16 + ln15) * D_HEAD
                                      + kc * 32 + lq * 8);

        f32x4 Oacc[4];
#pragma unroll
        for (int dn = 0; dn < 4; ++dn) Oacc[dn] = (f32x4){0.f, 0.f, 0.f, 0.f};
        float m_run = -INFINITY, l_run = 0.f;

        for (int t = 0; t < ntk; ++t) {
            const int kb = t * ATK;
            __syncthreads();   // prev iter's LDS reads (and prev-half epilogue) done
            // stage K tile [128][64]
#pragma unroll
            for (int i = 0; i < 4; ++i) {
                const int ch = tid + i * 256;
                const int r = ch >> 3, c8 = (ch & 7) * 8;
                *(bf16x8*)&Ks[r * KP + c8] =
                    *(const bf16x8*)(Kh + (size_t)(kb + r) * D_HEAD + c8);
            }
            // stage Vt tile [64][128]
#pragma unroll
            for (int i = 0; i < 4; ++i) {
                const int ch = tid + i * 256;
                const int r = ch >> 4, c8 = (ch & 15) * 8;
                *(bf16x8*)&Vts[r * VP + c8] =
                    *(const bf16x8*)(Vh + (size_t)r * SEQ_T + kb + c8);
            }
            __syncthreads();

            // ---- S^T[j=128][q=16] : A=K (rows j), B=Q (rows q), 16x16x32
            f32x4 st[8];
#pragma unroll
            for (int jf = 0; jf < 8; ++jf) st[jf] = (f32x4){0.f, 0.f, 0.f, 0.f};
#pragma unroll
            for (int jf = 0; jf < 8; ++jf) {
                const bf16x8 kf0 = *(const bf16x8*)&Ks[(jf * 16 + ln15) * KP + lq * 8];
                const bf16x8 kf1 = *(const bf16x8*)&Ks[(jf * 16 + ln15) * KP + 32 + lq * 8];
                st[jf] = __builtin_amdgcn_mfma_f32_16x16x32_bf16(kf0, qf[0], st[jf], 0, 0, 0);
                st[jf] = __builtin_amdgcn_mfma_f32_16x16x32_bf16(kf1, qf[1], st[jf], 0, 0, 0);
            }

            // ---- causal mask on the diagonal tile (raw-score domain)
            if (t == ntk - 1) {
#pragma unroll
                for (int jf = 0; jf < 8; ++jf)
#pragma unroll
                    for (int r = 0; r < 4; ++r)
                        if ((kb + jf * 16 + lq * 4 + r) > qg) st[jf][r] = -INFINITY;
            }

            // ---- online softmax for q=qg (raw max; exp2 with folded scale)
            float tmax = st[0][0];
#pragma unroll
            for (int jf = 0; jf < 8; ++jf)
#pragma unroll
                for (int r = 0; r < 4; ++r) tmax = fmaxf(tmax, st[jf][r]);
            tmax = fmaxf(tmax, __shfl_xor(tmax, 16));
            tmax = fmaxf(tmax, __shfl_xor(tmax, 32));
            const float mnew  = fmaxf(m_run, tmax);
            const float alpha = exp2f((m_run - mnew) * CEXP);
            const float mc    = mnew * CEXP;
            float psum = 0.f;
#pragma unroll
            for (int jf = 0; jf < 8; ++jf)
#pragma unroll
                for (int r = 0; r < 4; ++r) {
                    const float p = exp2f(fmaf(st[jf][r], CEXP, -mc));
                    st[jf][r] = p;
                    psum += p;
                }
            psum += __shfl_xor(psum, 16);
            psum += __shfl_xor(psum, 32);
            l_run = alpha * l_run + psum;
            m_run = mnew;

            float a4[4];
#pragma unroll
            for (int r = 0; r < 4; ++r) a4[r] = __shfl(alpha, lq * 4 + r);
#pragma unroll
            for (int dn = 0; dn < 4; ++dn)
#pragma unroll
                for (int r = 0; r < 4; ++r) Oacc[dn][r] *= a4[r];

            // ---- O += P V via 16x16x16: P-frag is the S^T C-fragment
#pragma unroll
            for (int jf = 0; jf < 8; ++jf) {
                s16x4 pfr;
#pragma unroll
                for (int s = 0; s < 4; ++s) {
                    __hip_bfloat16 e = __float2bfloat16(st[jf][s]);
                    pfr[s] = __builtin_bit_cast(short, e);
                }
#pragma unroll
                for (int dn = 0; dn < 4; ++dn) {
                    const s16x4 vfr = *(const s16x4*)&Vts[(dn * 16 + ln15) * VP
                                                          + jf * 16 + lq * 4];
                    Oacc[dn] = mfma16_bf16(pfr, vfr, Oacc[dn]);
                }
            }
        }

        // ---- epilogue: transpose O through Ks (barrier: Ks reuse after reads)
        __syncthreads();
        float il[4];
#pragma unroll
        for (int r = 0; r < 4; ++r) il[r] = 1.0f / __shfl(l_run, lq * 4 + r);
#pragma unroll
        for (int dn = 0; dn < 4; ++dn)
#pragma unroll
            for (int r = 0; r < 4; ++r)
                Ks[(wv * 16 + lq * 4 + r) * 72 + dn * 16 + ln15] =
                    __float2bfloat16(Oacc[dn][r] * il[r]);
        const int r2 = lane >> 3, c8 = (lane & 7) * 8;
#pragma unroll
        for (int i = 0; i < 2; ++i) {
            const int row = wv * 16 + r2 + 8 * i;
            const bf16x8 val = *(const bf16x8*)&Ks[row * 72 + c8];
            *(bf16x8*)(y + (bT + qbase + row) * D_MODEL + h * D_HEAD + c8) = val;
        }
    }
}

// ------------------------------------------------------------------ launch
extern "C" void kernel_launch(void* const* d_in, const int* in_sizes, int n_in,
                              void* d_out, int out_size, void* d_ws, size_t ws_size,
                              hipStream_t stream)
{
    const float* x      = (const float*)d_in[0];
    const float* ln1_w  = (const float*)d_in[1];
    const float* ln1_b  = (const float*)d_in[2];
    const float* attn_w = (const float*)d_in[3];
    const float* attn_b = (const float*)d_in[4];
    const float* proj_w = (const float*)d_in[5];
    const float* proj_b = (const float*)d_in[6];
    const float* ln2_w  = (const float*)d_in[7];
    const float* ln2_b  = (const float*)d_in[8];
    const float* fc_w   = (const float*)d_in[9];
    const float* fc_b   = (const float*)d_in[10];
    const float* fc2_w  = (const float*)d_in[11];
    const float* fc2_b  = (const float*)d_in[12];
    float* out = (float*)d_out;

    char* ws = (char*)d_ws;
    __hip_bfloat16* Qb      = (__hip_bfloat16*)(ws);
    __hip_bfloat16* Kb      = (__hip_bfloat16*)(ws + (size_t)8  * 1024 * 1024);
    __hip_bfloat16* Vtb     = (__hip_bfloat16*)(ws + (size_t)16 * 1024 * 1024);
    __hip_bfloat16* h_bf    = (__hip_bfloat16*)(ws);
    __hip_bfloat16* ln_buf  = (__hip_bfloat16*)(ws + (size_t)32 * 1024 * 1024);
    __hip_bfloat16* y_buf   = (__hip_bfloat16*)(ws + (size_t)40 * 1024 * 1024);
    float*          xmid    = (float*)(ws + (size_t)48 * 1024 * 1024);
    __hip_bfloat16* attn_wt = (__hip_bfloat16*)(ws + (size_t)64 * 1024 * 1024);
    __hip_bfloat16* proj_wt = (__hip_bfloat16*)(ws + (size_t)70 * 1024 * 1024);
    __hip_bfloat16* fc_wt   = (__hip_bfloat16*)(ws + (size_t)72 * 1024 * 1024);
    __hip_bfloat16* fc2_wt  = (__hip_bfloat16*)(ws + (size_t)80 * 1024 * 1024);

    dim3 blk256(256);
    dim3 blk512(512);

    // 0. all weight transposes in one launch (fp32 [K,N] -> bf16 [N,K])
    transpose_all_kernel<<<dim3(12288), blk256, 0, stream>>>(
        attn_w, proj_w, fc_w, fc2_w, attn_wt, proj_wt, fc_wt, fc2_wt);

    // 1. ln1(x) -> ln_buf (bf16)
    ln_kernel<<<dim3(NROWS), blk256, 0, stream>>>(x, ln1_w, ln1_b, ln_buf, D_MODEL);

    // 2. qkv GEMM (rot4 256x256) -> Qb/Kb/Vtb   grid 12x16 = 192
    qkv256_kernel<<<dim3(C3 / 256, NROWS / 256), blk512, 0, stream>>>(
        ln_buf, attn_wt, attn_b, Qb, Kb, Vtb);

    // 3. MFMA flash attention v4 -> y_buf (bf16)
    mfma_attn_kernel<<<dim3(NQT / 2, N_HEAD, BATCH), blk256, 0, stream>>>(
        Qb, Kb, Vtb, y_buf);

    // 4. xmid = x + y_buf @ proj_w + proj_b  (fp32, rot4 128x128, grid 256)
    gemm128_kernel<<<dim3(D_MODEL / 128, NROWS / 128), blk256, 0, stream>>>(
        y_buf, proj_wt, proj_b, x, xmid, NROWS, D_MODEL, D_MODEL, 0, 0);

    // 5. ln2(xmid) -> ln_buf (bf16)
    ln_kernel<<<dim3(NROWS), blk256, 0, stream>>>(xmid, ln2_w, ln2_b, ln_buf, D_MODEL);

    // 6. h = gelu(ln_buf @ fc_w + fc_b) -> bf16 (rot4 256x256, grid 256)
    gemm256_kernel<<<dim3(D_FF / 256, NROWS / 256), blk512, 0, stream>>>(
        ln_buf, fc_wt, fc_b, nullptr, h_bf, NROWS, D_FF, D_MODEL, 1, 1);

    // 7. out = xmid + h @ fc2_w + fc2_b  (fp32, rot4 128x128, grid 256)
    gemm128_kernel<<<dim3(D_MODEL / 128, NROWS / 128), blk256, 0, stream>>>(
        h_bf, fc2_wt, fc2_b, xmid, out, NROWS, D_MODEL, D_FF, 0, 0);
}

// Round 4
// 388.566 us; speedup vs baseline: 1.4645x; 1.0394x over previous
//
#include <hip/hip_runtime.h>
#include <hip/hip_bf16.h>
#include <math.h>

// Transformer block. Round 15: attention v5 — (1) head-locality XCD remap
// (R14 FETCH was 122MB: every head's K/V pulled into all 8 XCD L2s; remap
// pins heads h%8==xcd -> 2MB/XCD working set), (2) async reg-staged K/V
// double buffer (T14: issue t+1 loads during compute of t; plain
// __syncthreads discipline), (3) XOR-swizzled Ks[128][64]/Vts[64][128]
// (T2: R14 had 6.7M bank conflicts from 144B/272B padded rows),
// (4) setprio around attn MFMA clusters (T5).
// GEMM cores (rot4, race-fixed), LN, transpose unchanged from Round 14.
// D_MODEL=1024, N_HEAD=16, D_HEAD=64, EXP=4, B=2, T=2048, EPS=1e-5

#define D_MODEL 1024
#define N_HEAD  16
#define D_HEAD  64
#define SEQ_T   2048
#define BATCH   2
#define NROWS   (BATCH * SEQ_T)   // 4096
#define C3      (3 * D_MODEL)     // 3072
#define D_FF    (4 * D_MODEL)     // 4096

typedef __bf16 bf16x8 __attribute__((ext_vector_type(8)));
typedef __bf16 bf16x4t __attribute__((ext_vector_type(4)));
typedef short  s16x4  __attribute__((ext_vector_type(4)));
typedef float  f32x4  __attribute__((ext_vector_type(4)));

// one wait per K-tile: drains the 4 loads of tile t+1 (issued 2 tiles ago),
// leaves 8 outstanding (tiles t+2, t+3). Never 0 in the loop (T4).
// Followed by a barrier before anyone reads the drained data (race-free).
#define WAIT_VM8() asm volatile("s_waitcnt vmcnt(8)" ::: "memory")

// 16x16x16 bf16 MFMA: builtin name differs across ROCm versions.
__device__ __forceinline__ f32x4 mfma16_bf16(s16x4 a, s16x4 b, f32x4 c)
{
#if __has_builtin(__builtin_amdgcn_mfma_f32_16x16x16_bf16)
    return __builtin_amdgcn_mfma_f32_16x16x16_bf16(
        __builtin_bit_cast(bf16x4t, a), __builtin_bit_cast(bf16x4t, b), c, 0, 0, 0);
#else
    return __builtin_amdgcn_mfma_f32_16x16x16bf16_1k(a, b, c, 0, 0, 0);
#endif
}

// ---------------------------------------------------------------- LayerNorm
__global__ __launch_bounds__(256) void ln_kernel(
    const float* __restrict__ in, const float* __restrict__ w,
    const float* __restrict__ b, __hip_bfloat16* __restrict__ out, int D)
{
    const int row = blockIdx.x;
    const int tid = threadIdx.x;
    const float* x = in + (size_t)row * D;

    float s = 0.f, s2 = 0.f;
    for (int i = tid; i < D; i += 256) {
        float v = x[i];
        s += v; s2 += v * v;
    }
    __shared__ float rs[256], rs2[256];
    rs[tid] = s; rs2[tid] = s2;
    __syncthreads();
    for (int off = 128; off > 0; off >>= 1) {
        if (tid < off) { rs[tid] += rs[tid + off]; rs2[tid] += rs2[tid + off]; }
        __syncthreads();
    }
    const float mu   = rs[0] / D;
    const float var  = rs2[0] / D - mu * mu;
    const float rstd = rsqrtf(var + 1e-5f);

    __hip_bfloat16* o = out + (size_t)row * D;
    for (int i = tid; i < D; i += 256)
        o[i] = __float2bfloat16((x[i] - mu) * rstd * w[i] + b[i]);
}

// -------------------------------- merged weight transpose + bf16 cast (x4)
__global__ __launch_bounds__(256) void transpose_all_kernel(
    const float* __restrict__ attn_w, const float* __restrict__ proj_w,
    const float* __restrict__ fc_w,   const float* __restrict__ fc2_w,
    __hip_bfloat16* __restrict__ attn_wt, __hip_bfloat16* __restrict__ proj_wt,
    __hip_bfloat16* __restrict__ fc_wt,   __hip_bfloat16* __restrict__ fc2_wt)
{
    __shared__ float t[32][33];
    int tb = blockIdx.x;
    const float* W; __hip_bfloat16* Wt; int K, N;
    if (tb < 3072)      { W = attn_w; Wt = attn_wt; K = D_MODEL; N = C3; }
    else if (tb < 4096) { tb -= 3072; W = proj_w; Wt = proj_wt; K = D_MODEL; N = D_MODEL; }
    else if (tb < 8192) { tb -= 4096; W = fc_w;   Wt = fc_wt;   K = D_MODEL; N = D_FF; }
    else                { tb -= 8192; W = fc2_w;  Wt = fc2_wt;  K = D_FF;    N = D_MODEL; }
    const int ntx = N >> 5;
    const int k0 = (tb / ntx) * 32;
    const int n0 = (tb % ntx) * 32;

    const int tx = threadIdx.x & 31;
    const int ty = threadIdx.x >> 5;
#pragma unroll
    for (int i = 0; i < 4; ++i)
        t[ty + 8 * i][tx] = W[(size_t)(k0 + ty + 8 * i) * N + n0 + tx];
    __syncthreads();
#pragma unroll
    for (int i = 0; i < 4; ++i)
        Wt[(size_t)(n0 + ty + 8 * i) * K + k0 + tx] =
            __float2bfloat16(t[tx][ty + 8 * i]);
}

// ----------------------------------------------------------- helpers
__device__ __forceinline__ void async16(const __hip_bfloat16* g, __hip_bfloat16* l)
{
    __builtin_amdgcn_global_load_lds(
        (const __attribute__((address_space(1))) void*)g,
        (__attribute__((address_space(3))) void*)l, 16, 0, 0);
}

__device__ __forceinline__ float gelu_exact(float v)
{
    return 0.5f * v * (1.0f + erff(v * 0.70710678118654752f));
}

// XCD-contiguous work remap (T1). All GEMM grids here are %8 == 0.
__device__ __forceinline__ void swz_xcd(int& bx, int& by)
{
    const int nbx = gridDim.x;
    const int nwg = nbx * gridDim.y;
    int lin = blockIdx.y * nbx + blockIdx.x;
    const int per = nwg >> 3;
    lin = (lin & 7) * per + (lin >> 3);   // XCD x -> contiguous work chunk
    bx = lin % nbx;
    by = lin / nbx;
}

// ================== rot4 GEMM cores (BK=32, 4-slot rotation) ==============
// (unchanged from Round 14 — race-fixed drain->barrier->read order)

template<int NL, int TPB>
__device__ __forceinline__ void stage_slice(
    const __hip_bfloat16* __restrict__ g, int K,
    __hip_bfloat16* __restrict__ ldst, int tid)
{
#pragma unroll
    for (int i = 0; i < NL; ++i)
        async16(g + (size_t)(i * (TPB / 4)) * K, ldst + i * (TPB / 4) * 32 + tid * 8);
}

// ---------------- 256x256 core, 512 threads, 8 waves (2M x 4N), 128KB LDS
__device__ __forceinline__ void gemm_rot4_512(
    const __hip_bfloat16* __restrict__ A,
    const __hip_bfloat16* __restrict__ Bt,
    int K, int row0, int col0, f32x4 (&acc)[8][4])
{
    __shared__ __align__(16) __hip_bfloat16 Asl[4][256 * 32];
    __shared__ __align__(16) __hip_bfloat16 Bsl[4][256 * 32];

    const int tid  = threadIdx.x;
    const int wv   = tid >> 6;
    const int lane = tid & 63;
    const int ln15 = lane & 15;
    const int lq   = lane >> 4;
    const int mbase = (wv >> 2) * 128;
    const int nbase = (wv & 3) * 64;
    const int rcol = (lq ^ ((ln15 >> 1) & 3)) * 8;
    const int ssw  = ((tid & 3) ^ ((tid >> 3) & 3)) * 8;
    const __hip_bfloat16* Ab = A  + (size_t)(row0 + (tid >> 2)) * K + ssw;
    const __hip_bfloat16* Bb = Bt + (size_t)(col0 + (tid >> 2)) * K + ssw;
    const int nt = K >> 5;   // K-tiles of 32; callers pass K % 128 == 0

#pragma unroll
    for (int mi = 0; mi < 8; ++mi)
#pragma unroll
        for (int ni = 0; ni < 4; ++ni) acc[mi][ni] = (f32x4){0.f, 0.f, 0.f, 0.f};

    // prologue: tiles 0,1,2 -> slots 0,1,2 (12 loads/wave); drain tile 0,
    // then barrier so EVERY wave's tile-0 loads have landed before reads.
#pragma unroll
    for (int t = 0; t < 3; ++t) {
        stage_slice<2, 512>(Ab + t * 32, K, &Asl[t][0], tid);
        stage_slice<2, 512>(Bb + t * 32, K, &Bsl[t][0], tid);
    }
    WAIT_VM8();
    __builtin_amdgcn_s_barrier();

    for (int tq = 0; tq < nt; tq += 4) {
#pragma unroll
        for (int u = 0; u < 4; ++u) {
            const int t   = tq + u;
            const int tcl = (t + 3 < nt) ? t + 3 : nt - 1;
            const int sl  = u;             // t & 3
            const int sl3 = (u + 3) & 3;   // (t+3) & 3
            bf16x8 af[4], bfr[4];

            // ---- phase 0: m-frags 0-3 (rows mbase..mbase+63)
#pragma unroll
            for (int mi = 0; mi < 4; ++mi)
                af[mi] = *(const bf16x8*)&Asl[sl][(mbase + mi * 16 + ln15) * 32 + rcol];
#pragma unroll
            for (int ni = 0; ni < 4; ++ni)
                bfr[ni] = *(const bf16x8*)&Bsl[sl][(nbase + ni * 16 + ln15) * 32 + rcol];
            stage_slice<2, 512>(Ab + (size_t)tcl * 32, K, &Asl[sl3][0], tid);
            __builtin_amdgcn_s_barrier();
            __builtin_amdgcn_s_setprio(1);
#pragma unroll
            for (int mi = 0; mi < 4; ++mi)
#pragma unroll
                for (int ni = 0; ni < 4; ++ni)
                    acc[mi][ni] = __builtin_amdgcn_mfma_f32_16x16x32_bf16(
                        af[mi], bfr[ni], acc[mi][ni], 0, 0, 0);
            __builtin_amdgcn_s_setprio(0);
            __builtin_amdgcn_s_barrier();

            // ---- phase 1: m-frags 4-7 (rows mbase+64..mbase+127)
#pragma unroll
            for (int mi = 0; mi < 4; ++mi)
                af[mi] = *(const bf16x8*)&Asl[sl][(mbase + 64 + mi * 16 + ln15) * 32 + rcol];
            stage_slice<2, 512>(Bb + (size_t)tcl * 32, K, &Bsl[sl3][0], tid);
            WAIT_VM8();                    // drain tile t+1 BEFORE barrier
            __builtin_amdgcn_s_barrier();
            __builtin_amdgcn_s_setprio(1);
#pragma unroll
            for (int mi = 0; mi < 4; ++mi)
#pragma unroll
                for (int ni = 0; ni < 4; ++ni)
                    acc[4 + mi][ni] = __builtin_amdgcn_mfma_f32_16x16x32_bf16(
                        af[mi], bfr[ni], acc[4 + mi][ni], 0, 0, 0);
            __builtin_amdgcn_s_setprio(0);
            __builtin_amdgcn_s_barrier();
        }
    }
}

// ---------------- 128x128 core, 256 threads, 4 waves (2M x 2N), 64KB LDS
__device__ __forceinline__ void gemm_rot4_256(
    const __hip_bfloat16* __restrict__ A,
    const __hip_bfloat16* __restrict__ Bt,
    int K, int row0, int col0, f32x4 (&acc)[4][4])
{
    __shared__ __align__(16) __hip_bfloat16 Asl[4][128 * 32];
    __shared__ __align__(16) __hip_bfloat16 Bsl[4][128 * 32];

    const int tid  = threadIdx.x;
    const int wv   = tid >> 6;
    const int lane = tid & 63;
    const int ln15 = lane & 15;
    const int lq   = lane >> 4;
    const int mbase = (wv >> 1) * 64;
    const int nbase = (wv & 1) * 64;
    const int rcol = (lq ^ ((ln15 >> 1) & 3)) * 8;
    const int ssw  = ((tid & 3) ^ ((tid >> 3) & 3)) * 8;
    const __hip_bfloat16* Ab = A  + (size_t)(row0 + (tid >> 2)) * K + ssw;
    const __hip_bfloat16* Bb = Bt + (size_t)(col0 + (tid >> 2)) * K + ssw;
    const int nt = K >> 5;

#pragma unroll
    for (int mi = 0; mi < 4; ++mi)
#pragma unroll
        for (int ni = 0; ni < 4; ++ni) acc[mi][ni] = (f32x4){0.f, 0.f, 0.f, 0.f};

#pragma unroll
    for (int t = 0; t < 3; ++t) {
        stage_slice<2, 256>(Ab + t * 32, K, &Asl[t][0], tid);
        stage_slice<2, 256>(Bb + t * 32, K, &Bsl[t][0], tid);
    }
    WAIT_VM8();
    __builtin_amdgcn_s_barrier();

    for (int tq = 0; tq < nt; tq += 4) {
#pragma unroll
        for (int u = 0; u < 4; ++u) {
            const int t   = tq + u;
            const int tcl = (t + 3 < nt) ? t + 3 : nt - 1;
            const int sl  = u;
            const int sl3 = (u + 3) & 3;
            bf16x8 af[4], bfr[4];

#pragma unroll
            for (int mi = 0; mi < 4; ++mi)
                af[mi] = *(const bf16x8*)&Asl[sl][(mbase + mi * 16 + ln15) * 32 + rcol];
#pragma unroll
            for (int ni = 0; ni < 4; ++ni)
                bfr[ni] = *(const bf16x8*)&Bsl[sl][(nbase + ni * 16 + ln15) * 32 + rcol];
            stage_slice<2, 256>(Ab + (size_t)tcl * 32, K, &Asl[sl3][0], tid);
            stage_slice<2, 256>(Bb + (size_t)tcl * 32, K, &Bsl[sl3][0], tid);
            WAIT_VM8();                    // drain tile t+1 BEFORE barrier
            __builtin_amdgcn_s_barrier();
            __builtin_amdgcn_s_setprio(1);
#pragma unroll
            for (int mi = 0; mi < 4; ++mi)
#pragma unroll
                for (int ni = 0; ni < 4; ++ni)
                    acc[mi][ni] = __builtin_amdgcn_mfma_f32_16x16x32_bf16(
                        af[mi], bfr[ni], acc[mi][ni], 0, 0, 0);
            __builtin_amdgcn_s_setprio(0);
            __builtin_amdgcn_s_barrier();
        }
    }
}

// ---------------- 256x256 kernel (fc1)
__global__ __launch_bounds__(512) void gemm256_kernel(
    const __hip_bfloat16* __restrict__ A,   // [M,K]
    const __hip_bfloat16* __restrict__ Bt,  // [N,K]
    const float* __restrict__ bias,         // [N]
    const float* __restrict__ residual,     // [M,N] or null
    void* __restrict__ Cout,                // [M,N] fp32 or bf16
    int M, int N, int K, int act, int outBf16)
{
    int bx, by;
    swz_xcd(bx, by);
    const int row0 = by * 256;
    const int col0 = bx * 256;

    f32x4 acc[8][4];
    gemm_rot4_512(A, Bt, K, row0, col0, acc);

    const int tid  = threadIdx.x;
    const int wv   = tid >> 6;
    const int lane = tid & 63;
    const int ln15 = lane & 15;
    const int lq   = lane >> 4;
    const int mbase = (wv >> 2) * 128;
    const int nbase = (wv & 3) * 64;

#pragma unroll
    for (int mi = 0; mi < 8; ++mi) {
#pragma unroll
        for (int ni = 0; ni < 4; ++ni) {
            const int gc = col0 + nbase + ni * 16 + ln15;
            const float bv = bias[gc];
#pragma unroll
            for (int r = 0; r < 4; ++r) {
                const int gr = row0 + mbase + mi * 16 + lq * 4 + r;
                float v = acc[mi][ni][r] + bv;
                if (act == 1) v = gelu_exact(v);
                if (residual) v += residual[(size_t)gr * N + gc];
                if (outBf16)
                    ((__hip_bfloat16*)Cout)[(size_t)gr * N + gc] = __float2bfloat16(v);
                else
                    ((float*)Cout)[(size_t)gr * N + gc] = v;
            }
        }
    }
}

// ---------------- 128x128 kernel (proj, fc2)
__global__ __launch_bounds__(256, 2) void gemm128_kernel(
    const __hip_bfloat16* __restrict__ A,
    const __hip_bfloat16* __restrict__ Bt,
    const float* __restrict__ bias,
    const float* __restrict__ residual,
    void* __restrict__ Cout,
    int M, int N, int K, int act, int outBf16)
{
    int bx, by;
    swz_xcd(bx, by);
    const int row0 = by * 128;
    const int col0 = bx * 128;

    f32x4 acc[4][4];
    gemm_rot4_256(A, Bt, K, row0, col0, acc);

    const int tid  = threadIdx.x;
    const int wv   = tid >> 6;
    const int lane = tid & 63;
    const int ln15 = lane & 15;
    const int lq   = lane >> 4;
    const int mbase = (wv >> 1) * 64;
    const int nbase = (wv & 1) * 64;

#pragma unroll
    for (int mi = 0; mi < 4; ++mi) {
#pragma unroll
        for (int ni = 0; ni < 4; ++ni) {
            const int gc = col0 + nbase + ni * 16 + ln15;
            const float bv = bias[gc];
#pragma unroll
            for (int r = 0; r < 4; ++r) {
                const int gr = row0 + mbase + mi * 16 + lq * 4 + r;
                float v = acc[mi][ni][r] + bv;
                if (act == 1) v = gelu_exact(v);
                if (residual) v += residual[(size_t)gr * N + gc];
                if (outBf16)
                    ((__hip_bfloat16*)Cout)[(size_t)gr * N + gc] = __float2bfloat16(v);
                else
                    ((float*)Cout)[(size_t)gr * N + gc] = v;
            }
        }
    }
}

// ---------------- qkv kernel (256x256 core) with routing epilogue
__global__ __launch_bounds__(512) void qkv256_kernel(
    const __hip_bfloat16* __restrict__ A,
    const __hip_bfloat16* __restrict__ Bt,
    const float* __restrict__ bias,
    __hip_bfloat16* __restrict__ Qb,
    __hip_bfloat16* __restrict__ Kb,
    __hip_bfloat16* __restrict__ Vtb)
{
    int bx, by;
    swz_xcd(bx, by);
    const int row0 = by * 256;
    const int col0 = bx * 256;

    f32x4 acc[8][4];
    gemm_rot4_512(A, Bt, D_MODEL, row0, col0, acc);

    const int tid  = threadIdx.x;
    const int wv   = tid >> 6;
    const int lane = tid & 63;
    const int ln15 = lane & 15;
    const int lq   = lane >> 4;
    const int mbase = (wv >> 2) * 128;
    const int nbase = (wv & 3) * 64;

#pragma unroll
    for (int mi = 0; mi < 8; ++mi) {
        const int gr0 = row0 + mbase + mi * 16 + lq * 4;   // + r
        const int bb  = gr0 >> 11;
        const int q0  = gr0 & 2047;
#pragma unroll
        for (int ni = 0; ni < 4; ++ni) {
            const int gc  = col0 + nbase + ni * 16 + ln15;
            const float bv = bias[gc];
            const int sec = gc >> 10;            // 0:Q 1:K 2:V
            const int hd  = (gc & 1023) >> 6;
            const int d   = gc & 63;
            if (sec == 2) {
                unsigned short u[4];
#pragma unroll
                for (int r = 0; r < 4; ++r) {
                    __hip_bfloat16 e = __float2bfloat16(acc[mi][ni][r] + bv);
                    u[r] = *(unsigned short*)&e;
                }
                uint2 pk;
                pk.x = (unsigned int)u[0] | ((unsigned int)u[1] << 16);
                pk.y = (unsigned int)u[2] | ((unsigned int)u[3] << 16);
                *(uint2*)(Vtb + ((size_t)((bb * N_HEAD + hd) * D_HEAD + d)) * SEQ_T + q0) = pk;
            } else {
                __hip_bfloat16* dst = (sec == 0 ? Qb : Kb)
                    + ((size_t)((bb * N_HEAD + hd) * SEQ_T + q0)) * D_HEAD + d;
#pragma unroll
                for (int r = 0; r < 4; ++r)
                    dst[(size_t)r * D_HEAD] = __float2bfloat16(acc[mi][ni][r] + bv);
            }
        }
    }
}

// ------------------------------------------------- MFMA flash attention v5
// 4 waves x 16 q-rows; each block: q-tile pair (qt, 31-qt) for one (h,b).
// Head-locality remap: XCD = flat&7 owns heads h%8==xcd -> K/V L2-resident.
// K/V reg-staged double buffer: issue tile t+1 global loads during tile t
// compute (T14). Ks[128][64] XOR16-swizzled, Vts[64][128] XOR8-swizzled
// (T2, both sides). S^T via 16x16x32 (A=K,B=Q); PV via 16x16x16 from the
// S^T C-fragment. Epilogue O-transpose through Ks scratch.
#define ATQ 64
#define ATK 128
#define NQT (SEQ_T / ATQ)   // 32

__global__ __launch_bounds__(256) void mfma_attn_kernel(
    const __hip_bfloat16* __restrict__ Qb,
    const __hip_bfloat16* __restrict__ Kb,
    const __hip_bfloat16* __restrict__ Vtb,
    __hip_bfloat16* __restrict__ y)
{
    __shared__ __align__(16) __hip_bfloat16 Ks[ATK * D_HEAD];   // [j][d] swz; O-scratch
    __shared__ __align__(16) __hip_bfloat16 Vts[D_HEAD * ATK];  // [d][j] swz

    // ---- head-locality remap: flat = (slot<<3)|xcd; slot = (hb<<4)|pair
    const int flat = (blockIdx.z * gridDim.y + blockIdx.y) * gridDim.x + blockIdx.x;
    const int xcd  = flat & 7;
    const int slot = flat >> 3;
    const int pair = slot & 15;          // 0..15
    const int hb   = slot >> 4;          // 0..3
    const int h    = xcd + 8 * (hb & 1);
    const int b    = hb >> 1;

    const int tid  = threadIdx.x;
    const int wv   = tid >> 6;
    const int lane = tid & 63;
    const int ln15 = lane & 15;
    const int lq   = lane >> 4;

    const __hip_bfloat16* Qh = Qb  + (size_t)(b * N_HEAD + h) * SEQ_T * D_HEAD;
    const __hip_bfloat16* Kh = Kb  + (size_t)(b * N_HEAD + h) * SEQ_T * D_HEAD;
    const __hip_bfloat16* Vh = Vtb + (size_t)(b * N_HEAD + h) * D_HEAD * SEQ_T;
    const size_t bT = (size_t)b * SEQ_T;

    const float CEXP = 0.18033688011f;   // 0.125 * log2(e)

    // staging registers (per-thread 1/4 of each tile row-chunk)
    bf16x8 kreg[4], vreg[4];
    const int kr = tid >> 3, kg = tid & 7;      // K: row base, 16B granule
    const int vr = tid >> 4, vc = tid & 15;     // V: row base, 16B granule

    auto issue = [&](int kb) {
#pragma unroll
        for (int i = 0; i < 4; ++i)
            kreg[i] = *(const bf16x8*)(Kh + (size_t)(kb + kr + i * 32) * D_HEAD + kg * 8);
#pragma unroll
        for (int i = 0; i < 4; ++i)
            vreg[i] = *(const bf16x8*)(Vh + (size_t)(vr + i * 16) * SEQ_T + kb + vc * 8);
    };
    auto commit = [&]() {
#pragma unroll
        for (int i = 0; i < 4; ++i) {
            const int r = kr + i * 32;
            *(bf16x8*)&Ks[r * 64 + ((kg ^ (r & 7)) << 3)] = kreg[i];
        }
#pragma unroll
        for (int i = 0; i < 4; ++i) {
            const int r = vr + i * 16;
            const int g8 = vc * 2;                       // 8B granule (even)
            *(bf16x8*)&Vts[r * 128 + ((g8 ^ ((r & 3) << 2)) << 2)] = vreg[i];
        }
    };

#pragma unroll 1
    for (int half = 0; half < 2; ++half) {
        const int qt    = half == 0 ? pair : (NQT - 1 - pair);
        const int qbase = qt * ATQ;
        const int ntk   = (qt >> 1) + 1;
        const int qg    = qbase + wv * 16 + ln15;   // stats-owner q row

        bf16x8 qf[2];
#pragma unroll
        for (int kc = 0; kc < 2; ++kc)
            qf[kc] = *(const bf16x8*)(Qh + (size_t)(qbase + wv * 16 + ln15) * D_HEAD
                                      + kc * 32 + lq * 8);

        f32x4 Oacc[4];
#pragma unroll
        for (int dn = 0; dn < 4; ++dn) Oacc[dn] = (f32x4){0.f, 0.f, 0.f, 0.f};
        float m_run = -INFINITY, l_run = 0.f;

        issue(0);

        for (int t = 0; t < ntk; ++t) {
            const int kb = t * ATK;
            commit();                       // regs(t) -> LDS (auto vmcnt wait)
            __syncthreads();                // writes visible to all waves
            if (t + 1 < ntk) issue((t + 1) * ATK);   // prefetch under compute

            // ---- S^T[j=128][q=16] : A=K (rows j), B=Q (rows q), 16x16x32
            f32x4 st[8];
#pragma unroll
            for (int jf = 0; jf < 8; ++jf) st[jf] = (f32x4){0.f, 0.f, 0.f, 0.f};
            __builtin_amdgcn_s_setprio(1);
#pragma unroll
            for (int jf = 0; jf < 8; ++jf) {
                const int rw = jf * 16 + ln15;
                const bf16x8 kf0 = *(const bf16x8*)&Ks[rw * 64 + ((lq ^ (ln15 & 7)) << 3)];
                const bf16x8 kf1 = *(const bf16x8*)&Ks[rw * 64 + (((4 + lq) ^ (ln15 & 7)) << 3)];
                st[jf] = __builtin_amdgcn_mfma_f32_16x16x32_bf16(kf0, qf[0], st[jf], 0, 0, 0);
                st[jf] = __builtin_amdgcn_mfma_f32_16x16x32_bf16(kf1, qf[1], st[jf], 0, 0, 0);
            }
            __builtin_amdgcn_s_setprio(0);

            // ---- causal mask on the diagonal tile (raw-score domain)
            if (t == ntk - 1) {
#pragma unroll
                for (int jf = 0; jf < 8; ++jf)
#pragma unroll
                    for (int r = 0; r < 4; ++r)
                        if ((kb + jf * 16 + lq * 4 + r) > qg) st[jf][r] = -INFINITY;
            }

            // ---- online softmax for q=qg (raw max; exp2 with folded scale)
            float tmax = st[0][0];
#pragma unroll
            for (int jf = 0; jf < 8; ++jf)
#pragma unroll
                for (int r = 0; r < 4; ++r) tmax = fmaxf(tmax, st[jf][r]);
            tmax = fmaxf(tmax, __shfl_xor(tmax, 16));
            tmax = fmaxf(tmax, __shfl_xor(tmax, 32));
            const float mnew  = fmaxf(m_run, tmax);
            const float alpha = exp2f((m_run - mnew) * CEXP);
            const float mc    = mnew * CEXP;
            float psum = 0.f;
#pragma unroll
            for (int jf = 0; jf < 8; ++jf)
#pragma unroll
                for (int r = 0; r < 4; ++r) {
                    const float p = exp2f(fmaf(st[jf][r], CEXP, -mc));
                    st[jf][r] = p;
                    psum += p;
                }
            psum += __shfl_xor(psum, 16);
            psum += __shfl_xor(psum, 32);
            l_run = alpha * l_run + psum;
            m_run = mnew;

            float a4[4];
#pragma unroll
            for (int r = 0; r < 4; ++r) a4[r] = __shfl(alpha, lq * 4 + r);
#pragma unroll
            for (int dn = 0; dn < 4; ++dn)
#pragma unroll
                for (int r = 0; r < 4; ++r) Oacc[dn][r] *= a4[r];

            // ---- O += P V via 16x16x16: P-frag is the S^T C-fragment
            __builtin_amdgcn_s_setprio(1);
#pragma unroll
            for (int jf = 0; jf < 8; ++jf) {
                s16x4 pfr;
#pragma unroll
                for (int s = 0; s < 4; ++s) {
                    __hip_bfloat16 e = __float2bfloat16(st[jf][s]);
                    pfr[s] = __builtin_bit_cast(short, e);
                }
#pragma unroll
                for (int dn = 0; dn < 4; ++dn) {
                    const int rw = dn * 16 + ln15;
                    const int g8 = (jf * 4 + lq) ^ ((ln15 & 3) << 2);
                    const s16x4 vfr = *(const s16x4*)&Vts[rw * 128 + (g8 << 2)];
                    Oacc[dn] = mfma16_bf16(pfr, vfr, Oacc[dn]);
                }
            }
            __builtin_amdgcn_s_setprio(0);
            __syncthreads();                // all reads done before next commit
        }

        // ---- epilogue: transpose O through Ks scratch (all reads barriered)
        float il[4];
#pragma unroll
        for (int r = 0; r < 4; ++r) il[r] = 1.0f / __shfl(l_run, lq * 4 + r);
#pragma unroll
        for (int dn = 0; dn < 4; ++dn)
#pragma unroll
            for (int r = 0; r < 4; ++r)
                Ks[(wv * 16 + lq * 4 + r) * 72 + dn * 16 + ln15] =
                    __float2bfloat16(Oacc[dn][r] * il[r]);
        const int r2 = lane >> 3, c8 = (lane & 7) * 8;
#pragma unroll
        for (int i = 0; i < 2; ++i) {
            const int row = wv * 16 + r2 + 8 * i;
            const bf16x8 val = *(const bf16x8*)&Ks[row * 72 + c8];
            *(bf16x8*)(y + (bT + qbase + row) * D_MODEL + h * D_HEAD + c8) = val;
        }
        __syncthreads();                    // Ks scratch free before next half
    }
}

// ------------------------------------------------------------------ launch
extern "C" void kernel_launch(void* const* d_in, const int* in_sizes, int n_in,
                              void* d_out, int out_size, void* d_ws, size_t ws_size,
                              hipStream_t stream)
{
    const float* x      = (const float*)d_in[0];
    const float* ln1_w  = (const float*)d_in[1];
    const float* ln1_b  = (const float*)d_in[2];
    const float* attn_w = (const float*)d_in[3];
    const float* attn_b = (const float*)d_in[4];
    const float* proj_w = (const float*)d_in[5];
    const float* proj_b = (const float*)d_in[6];
    const float* ln2_w  = (const float*)d_in[7];
    const float* ln2_b  = (const float*)d_in[8];
    const float* fc_w   = (const float*)d_in[9];
    const float* fc_b   = (const float*)d_in[10];
    const float* fc2_w  = (const float*)d_in[11];
    const float* fc2_b  = (const float*)d_in[12];
    float* out = (float*)d_out;

    char* ws = (char*)d_ws;
    __hip_bfloat16* Qb      = (__hip_bfloat16*)(ws);
    __hip_bfloat16* Kb      = (__hip_bfloat16*)(ws + (size_t)8  * 1024 * 1024);
    __hip_bfloat16* Vtb     = (__hip_bfloat16*)(ws + (size_t)16 * 1024 * 1024);
    __hip_bfloat16* h_bf    = (__hip_bfloat16*)(ws);
    __hip_bfloat16* ln_buf  = (__hip_bfloat16*)(ws + (size_t)32 * 1024 * 1024);
    __hip_bfloat16* y_buf   = (__hip_bfloat16*)(ws + (size_t)40 * 1024 * 1024);
    float*          xmid    = (float*)(ws + (size_t)48 * 1024 * 1024);
    __hip_bfloat16* attn_wt = (__hip_bfloat16*)(ws + (size_t)64 * 1024 * 1024);
    __hip_bfloat16* proj_wt = (__hip_bfloat16*)(ws + (size_t)70 * 1024 * 1024);
    __hip_bfloat16* fc_wt   = (__hip_bfloat16*)(ws + (size_t)72 * 1024 * 1024);
    __hip_bfloat16* fc2_wt  = (__hip_bfloat16*)(ws + (size_t)80 * 1024 * 1024);

    dim3 blk256(256);
    dim3 blk512(512);

    // 0. all weight transposes in one launch (fp32 [K,N] -> bf16 [N,K])
    transpose_all_kernel<<<dim3(12288), blk256, 0, stream>>>(
        attn_w, proj_w, fc_w, fc2_w, attn_wt, proj_wt, fc_wt, fc2_wt);

    // 1. ln1(x) -> ln_buf (bf16)
    ln_kernel<<<dim3(NROWS), blk256, 0, stream>>>(x, ln1_w, ln1_b, ln_buf, D_MODEL);

    // 2. qkv GEMM (rot4 256x256) -> Qb/Kb/Vtb   grid 12x16 = 192
    qkv256_kernel<<<dim3(C3 / 256, NROWS / 256), blk512, 0, stream>>>(
        ln_buf, attn_wt, attn_b, Qb, Kb, Vtb);

    // 3. MFMA flash attention v5 -> y_buf (bf16)
    mfma_attn_kernel<<<dim3(NQT / 2, N_HEAD, BATCH), blk256, 0, stream>>>(
        Qb, Kb, Vtb, y_buf);

    // 4. xmid = x + y_buf @ proj_w + proj_b  (fp32, rot4 128x128, grid 256)
    gemm128_kernel<<<dim3(D_MODEL / 128, NROWS / 128), blk256, 0, stream>>>(
        y_buf, proj_wt, proj_b, x, xmid, NROWS, D_MODEL, D_MODEL, 0, 0);

    // 5. ln2(xmid) -> ln_buf (bf16)
    ln_kernel<<<dim3(NROWS), blk256, 0, stream>>>(xmid, ln2_w, ln2_b, ln_buf, D_MODEL);

    // 6. h = gelu(ln_buf @ fc_w + fc_b) -> bf16 (rot4 256x256, grid 256)
    gemm256_kernel<<<dim3(D_FF / 256, NROWS / 256), blk512, 0, stream>>>(
        ln_buf, fc_wt, fc_b, nullptr, h_bf, NROWS, D_FF, D_MODEL, 1, 1);

    // 7. out = xmid + h @ fc2_w + fc2_b  (fp32, rot4 128x128, grid 256)
    gemm128_kernel<<<dim3(D_MODEL / 128, NROWS / 128), blk256, 0, stream>>>(
        h_bf, fc2_wt, fc2_b, xmid, out, NROWS, D_MODEL, D_FF, 0, 0);
}

// Round 5
// 360.222 us; speedup vs baseline: 1.5797x; 1.0787x over previous
//
#include <hip/hip_runtime.h>
#include <hip/hip_bf16.h>
#include <math.h>

// Transformer block. Round 16:
// (a) gemm128 core -> 8 waves / 512 threads (wave tile 32x64), same rot4
//     schedule (2 loads/tile -> vmcnt(4)). R15 ran fc2 at 1 wave/SIMD
//     (Occupancy 9.7%) -> all barrier/wait latency exposed; now 4/SIMD.
// (b) attention LDS: Ks split-half [2][128][32] reusing the GEMM pattern
//     that measured ZERO conflicts (R12-R14); Vts [64][136] padded, no XOR
//     (R15's hand-rolled swizzles RAISED conflicts 6.7M->13.4M and made
//     8B-aligned 16B stores). PV reads become 2-way (free).
// (c) everything else unchanged from R15 (head-locality remap FETCH
//     122->12MB verified; rot4_512 GEMMs; LN; transpose).
// D_MODEL=1024, N_HEAD=16, D_HEAD=64, EXP=4, B=2, T=2048, EPS=1e-5

#define D_MODEL 1024
#define N_HEAD  16
#define D_HEAD  64
#define SEQ_T   2048
#define BATCH   2
#define NROWS   (BATCH * SEQ_T)   // 4096
#define C3      (3 * D_MODEL)     // 3072
#define D_FF    (4 * D_MODEL)     // 4096

typedef __bf16 bf16x8 __attribute__((ext_vector_type(8)));
typedef __bf16 bf16x4t __attribute__((ext_vector_type(4)));
typedef short  s16x4  __attribute__((ext_vector_type(4)));
typedef float  f32x4  __attribute__((ext_vector_type(4)));

// counted vmcnt (T4): drain tile t+1's loads, keep later tiles in flight.
// Always followed by s_barrier before the drained data is ds_read.
#define WAIT_VM8() asm volatile("s_waitcnt vmcnt(8)" ::: "memory")
#define WAIT_VM4() asm volatile("s_waitcnt vmcnt(4)" ::: "memory")

// 16x16x16 bf16 MFMA: builtin name differs across ROCm versions.
__device__ __forceinline__ f32x4 mfma16_bf16(s16x4 a, s16x4 b, f32x4 c)
{
#if __has_builtin(__builtin_amdgcn_mfma_f32_16x16x16_bf16)
    return __builtin_amdgcn_mfma_f32_16x16x16_bf16(
        __builtin_bit_cast(bf16x4t, a), __builtin_bit_cast(bf16x4t, b), c, 0, 0, 0);
#else
    return __builtin_amdgcn_mfma_f32_16x16x16bf16_1k(a, b, c, 0, 0, 0);
#endif
}

// ---------------------------------------------------------------- LayerNorm
__global__ __launch_bounds__(256) void ln_kernel(
    const float* __restrict__ in, const float* __restrict__ w,
    const float* __restrict__ b, __hip_bfloat16* __restrict__ out, int D)
{
    const int row = blockIdx.x;
    const int tid = threadIdx.x;
    const float* x = in + (size_t)row * D;

    float s = 0.f, s2 = 0.f;
    for (int i = tid; i < D; i += 256) {
        float v = x[i];
        s += v; s2 += v * v;
    }
    __shared__ float rs[256], rs2[256];
    rs[tid] = s; rs2[tid] = s2;
    __syncthreads();
    for (int off = 128; off > 0; off >>= 1) {
        if (tid < off) { rs[tid] += rs[tid + off]; rs2[tid] += rs2[tid + off]; }
        __syncthreads();
    }
    const float mu   = rs[0] / D;
    const float var  = rs2[0] / D - mu * mu;
    const float rstd = rsqrtf(var + 1e-5f);

    __hip_bfloat16* o = out + (size_t)row * D;
    for (int i = tid; i < D; i += 256)
        o[i] = __float2bfloat16((x[i] - mu) * rstd * w[i] + b[i]);
}

// -------------------------------- merged weight transpose + bf16 cast (x4)
__global__ __launch_bounds__(256) void transpose_all_kernel(
    const float* __restrict__ attn_w, const float* __restrict__ proj_w,
    const float* __restrict__ fc_w,   const float* __restrict__ fc2_w,
    __hip_bfloat16* __restrict__ attn_wt, __hip_bfloat16* __restrict__ proj_wt,
    __hip_bfloat16* __restrict__ fc_wt,   __hip_bfloat16* __restrict__ fc2_wt)
{
    __shared__ float t[32][33];
    int tb = blockIdx.x;
    const float* W; __hip_bfloat16* Wt; int K, N;
    if (tb < 3072)      { W = attn_w; Wt = attn_wt; K = D_MODEL; N = C3; }
    else if (tb < 4096) { tb -= 3072; W = proj_w; Wt = proj_wt; K = D_MODEL; N = D_MODEL; }
    else if (tb < 8192) { tb -= 4096; W = fc_w;   Wt = fc_wt;   K = D_MODEL; N = D_FF; }
    else                { tb -= 8192; W = fc2_w;  Wt = fc2_wt;  K = D_FF;    N = D_MODEL; }
    const int ntx = N >> 5;
    const int k0 = (tb / ntx) * 32;
    const int n0 = (tb % ntx) * 32;

    const int tx = threadIdx.x & 31;
    const int ty = threadIdx.x >> 5;
#pragma unroll
    for (int i = 0; i < 4; ++i)
        t[ty + 8 * i][tx] = W[(size_t)(k0 + ty + 8 * i) * N + n0 + tx];
    __syncthreads();
#pragma unroll
    for (int i = 0; i < 4; ++i)
        Wt[(size_t)(n0 + ty + 8 * i) * K + k0 + tx] =
            __float2bfloat16(t[tx][ty + 8 * i]);
}

// ----------------------------------------------------------- helpers
__device__ __forceinline__ void async16(const __hip_bfloat16* g, __hip_bfloat16* l)
{
    __builtin_amdgcn_global_load_lds(
        (const __attribute__((address_space(1))) void*)g,
        (__attribute__((address_space(3))) void*)l, 16, 0, 0);
}

__device__ __forceinline__ float gelu_exact(float v)
{
    return 0.5f * v * (1.0f + erff(v * 0.70710678118654752f));
}

// XCD-contiguous work remap (T1). All GEMM grids here are %8 == 0.
__device__ __forceinline__ void swz_xcd(int& bx, int& by)
{
    const int nbx = gridDim.x;
    const int nwg = nbx * gridDim.y;
    int lin = blockIdx.y * nbx + blockIdx.x;
    const int per = nwg >> 3;
    lin = (lin & 7) * per + (lin >> 3);   // XCD x -> contiguous work chunk
    bx = lin % nbx;
    by = lin / nbx;
}

// ================== rot4 GEMM cores (BK=32, 4-slot rotation) ==============
// Race-fixed order per tile t: ds_read slot sl -> stage tile t+3 into sl3
// -> counted vmcnt (drains tile t+1) -> barrier -> MFMA -> barrier.
// Granule swizzle (T2, both sides): LDS granule g holds source granule
// g ^ ((row>>1)&3); reader at k-granule lq reads lq ^ ((row>>1)&3).
// Measured 0 conflicts (R12).

template<int NL, int TPB>
__device__ __forceinline__ void stage_slice(
    const __hip_bfloat16* __restrict__ g, int K,
    __hip_bfloat16* __restrict__ ldst, int tid)
{
#pragma unroll
    for (int i = 0; i < NL; ++i)
        async16(g + (size_t)(i * (TPB / 4)) * K, ldst + i * (TPB / 4) * 32 + tid * 8);
}

// ---------------- 256x256 core, 512 threads, 8 waves (2M x 4N), 128KB LDS
__device__ __forceinline__ void gemm_rot4_512(
    const __hip_bfloat16* __restrict__ A,
    const __hip_bfloat16* __restrict__ Bt,
    int K, int row0, int col0, f32x4 (&acc)[8][4])
{
    __shared__ __align__(16) __hip_bfloat16 Asl[4][256 * 32];
    __shared__ __align__(16) __hip_bfloat16 Bsl[4][256 * 32];

    const int tid  = threadIdx.x;
    const int wv   = tid >> 6;
    const int lane = tid & 63;
    const int ln15 = lane & 15;
    const int lq   = lane >> 4;
    const int mbase = (wv >> 2) * 128;
    const int nbase = (wv & 3) * 64;
    const int rcol = (lq ^ ((ln15 >> 1) & 3)) * 8;
    const int ssw  = ((tid & 3) ^ ((tid >> 3) & 3)) * 8;
    const __hip_bfloat16* Ab = A  + (size_t)(row0 + (tid >> 2)) * K + ssw;
    const __hip_bfloat16* Bb = Bt + (size_t)(col0 + (tid >> 2)) * K + ssw;
    const int nt = K >> 5;   // K-tiles of 32; callers pass K % 128 == 0

#pragma unroll
    for (int mi = 0; mi < 8; ++mi)
#pragma unroll
        for (int ni = 0; ni < 4; ++ni) acc[mi][ni] = (f32x4){0.f, 0.f, 0.f, 0.f};

#pragma unroll
    for (int t = 0; t < 3; ++t) {
        stage_slice<2, 512>(Ab + t * 32, K, &Asl[t][0], tid);
        stage_slice<2, 512>(Bb + t * 32, K, &Bsl[t][0], tid);
    }
    WAIT_VM8();
    __builtin_amdgcn_s_barrier();

    for (int tq = 0; tq < nt; tq += 4) {
#pragma unroll
        for (int u = 0; u < 4; ++u) {
            const int t   = tq + u;
            const int tcl = (t + 3 < nt) ? t + 3 : nt - 1;
            const int sl  = u;             // t & 3
            const int sl3 = (u + 3) & 3;   // (t+3) & 3
            bf16x8 af[4], bfr[4];

            // ---- phase 0: m-frags 0-3 (rows mbase..mbase+63)
#pragma unroll
            for (int mi = 0; mi < 4; ++mi)
                af[mi] = *(const bf16x8*)&Asl[sl][(mbase + mi * 16 + ln15) * 32 + rcol];
#pragma unroll
            for (int ni = 0; ni < 4; ++ni)
                bfr[ni] = *(const bf16x8*)&Bsl[sl][(nbase + ni * 16 + ln15) * 32 + rcol];
            stage_slice<2, 512>(Ab + (size_t)tcl * 32, K, &Asl[sl3][0], tid);
            __builtin_amdgcn_s_barrier();
            __builtin_amdgcn_s_setprio(1);
#pragma unroll
            for (int mi = 0; mi < 4; ++mi)
#pragma unroll
                for (int ni = 0; ni < 4; ++ni)
                    acc[mi][ni] = __builtin_amdgcn_mfma_f32_16x16x32_bf16(
                        af[mi], bfr[ni], acc[mi][ni], 0, 0, 0);
            __builtin_amdgcn_s_setprio(0);
            __builtin_amdgcn_s_barrier();

            // ---- phase 1: m-frags 4-7 (rows mbase+64..mbase+127)
#pragma unroll
            for (int mi = 0; mi < 4; ++mi)
                af[mi] = *(const bf16x8*)&Asl[sl][(mbase + 64 + mi * 16 + ln15) * 32 + rcol];
            stage_slice<2, 512>(Bb + (size_t)tcl * 32, K, &Bsl[sl3][0], tid);
            WAIT_VM8();                    // drain tile t+1 BEFORE barrier
            __builtin_amdgcn_s_barrier();
            __builtin_amdgcn_s_setprio(1);
#pragma unroll
            for (int mi = 0; mi < 4; ++mi)
#pragma unroll
                for (int ni = 0; ni < 4; ++ni)
                    acc[4 + mi][ni] = __builtin_amdgcn_mfma_f32_16x16x32_bf16(
                        af[mi], bfr[ni], acc[4 + mi][ni], 0, 0, 0);
            __builtin_amdgcn_s_setprio(0);
            __builtin_amdgcn_s_barrier();
        }
    }
}

// ---------------- 128x128 core, 512 threads, 8 waves (4M x 2N), 64KB LDS
// Wave tile 32x64 (acc[2][4]); 2 blocks/CU -> 4 waves/SIMD (R15 had 1).
// Ledger: 2 loads/tile; prologue 6; in-loop outstanding 6 -> vmcnt(4)
// drains tile t+1.
__device__ __forceinline__ void gemm_rot4_128x8(
    const __hip_bfloat16* __restrict__ A,
    const __hip_bfloat16* __restrict__ Bt,
    int K, int row0, int col0, f32x4 (&acc)[2][4])
{
    __shared__ __align__(16) __hip_bfloat16 Asl[4][128 * 32];
    __shared__ __align__(16) __hip_bfloat16 Bsl[4][128 * 32];

    const int tid  = threadIdx.x;
    const int wv   = tid >> 6;
    const int lane = tid & 63;
    const int ln15 = lane & 15;
    const int lq   = lane >> 4;
    const int mbase = (wv >> 1) * 32;
    const int nbase = (wv & 1) * 64;
    const int rcol = (lq ^ ((ln15 >> 1) & 3)) * 8;
    const int ssw  = ((tid & 3) ^ ((tid >> 3) & 3)) * 8;
    const __hip_bfloat16* Ab = A  + (size_t)(row0 + (tid >> 2)) * K + ssw;
    const __hip_bfloat16* Bb = Bt + (size_t)(col0 + (tid >> 2)) * K + ssw;
    const int nt = K >> 5;

#pragma unroll
    for (int mi = 0; mi < 2; ++mi)
#pragma unroll
        for (int ni = 0; ni < 4; ++ni) acc[mi][ni] = (f32x4){0.f, 0.f, 0.f, 0.f};

#pragma unroll
    for (int t = 0; t < 3; ++t) {
        stage_slice<1, 512>(Ab + t * 32, K, &Asl[t][0], tid);
        stage_slice<1, 512>(Bb + t * 32, K, &Bsl[t][0], tid);
    }
    WAIT_VM4();
    __builtin_amdgcn_s_barrier();

    for (int tq = 0; tq < nt; tq += 4) {
#pragma unroll
        for (int u = 0; u < 4; ++u) {
            const int t   = tq + u;
            const int tcl = (t + 3 < nt) ? t + 3 : nt - 1;
            const int sl  = u;
            const int sl3 = (u + 3) & 3;
            bf16x8 af[2], bfr[4];

#pragma unroll
            for (int mi = 0; mi < 2; ++mi)
                af[mi] = *(const bf16x8*)&Asl[sl][(mbase + mi * 16 + ln15) * 32 + rcol];
#pragma unroll
            for (int ni = 0; ni < 4; ++ni)
                bfr[ni] = *(const bf16x8*)&Bsl[sl][(nbase + ni * 16 + ln15) * 32 + rcol];
            stage_slice<1, 512>(Ab + (size_t)tcl * 32, K, &Asl[sl3][0], tid);
            stage_slice<1, 512>(Bb + (size_t)tcl * 32, K, &Bsl[sl3][0], tid);
            WAIT_VM4();                    // drain tile t+1 BEFORE barrier
            __builtin_amdgcn_s_barrier();
            __builtin_amdgcn_s_setprio(1);
#pragma unroll
            for (int mi = 0; mi < 2; ++mi)
#pragma unroll
                for (int ni = 0; ni < 4; ++ni)
                    acc[mi][ni] = __builtin_amdgcn_mfma_f32_16x16x32_bf16(
                        af[mi], bfr[ni], acc[mi][ni], 0, 0, 0);
            __builtin_amdgcn_s_setprio(0);
            __builtin_amdgcn_s_barrier();
        }
    }
}

// ---------------- 256x256 kernel (fc1)
__global__ __launch_bounds__(512) void gemm256_kernel(
    const __hip_bfloat16* __restrict__ A,   // [M,K]
    const __hip_bfloat16* __restrict__ Bt,  // [N,K]
    const float* __restrict__ bias,         // [N]
    const float* __restrict__ residual,     // [M,N] or null
    void* __restrict__ Cout,                // [M,N] fp32 or bf16
    int M, int N, int K, int act, int outBf16)
{
    int bx, by;
    swz_xcd(bx, by);
    const int row0 = by * 256;
    const int col0 = bx * 256;

    f32x4 acc[8][4];
    gemm_rot4_512(A, Bt, K, row0, col0, acc);

    const int tid  = threadIdx.x;
    const int wv   = tid >> 6;
    const int lane = tid & 63;
    const int ln15 = lane & 15;
    const int lq   = lane >> 4;
    const int mbase = (wv >> 2) * 128;
    const int nbase = (wv & 3) * 64;

#pragma unroll
    for (int mi = 0; mi < 8; ++mi) {
#pragma unroll
        for (int ni = 0; ni < 4; ++ni) {
            const int gc = col0 + nbase + ni * 16 + ln15;
            const float bv = bias[gc];
#pragma unroll
            for (int r = 0; r < 4; ++r) {
                const int gr = row0 + mbase + mi * 16 + lq * 4 + r;
                float v = acc[mi][ni][r] + bv;
                if (act == 1) v = gelu_exact(v);
                if (residual) v += residual[(size_t)gr * N + gc];
                if (outBf16)
                    ((__hip_bfloat16*)Cout)[(size_t)gr * N + gc] = __float2bfloat16(v);
                else
                    ((float*)Cout)[(size_t)gr * N + gc] = v;
            }
        }
    }
}

// ---------------- 128x128 kernel (proj, fc2) — 8 waves
__global__ __launch_bounds__(512, 2) void gemm128_kernel(
    const __hip_bfloat16* __restrict__ A,
    const __hip_bfloat16* __restrict__ Bt,
    const float* __restrict__ bias,
    const float* __restrict__ residual,
    void* __restrict__ Cout,
    int M, int N, int K, int act, int outBf16)
{
    int bx, by;
    swz_xcd(bx, by);
    const int row0 = by * 128;
    const int col0 = bx * 128;

    f32x4 acc[2][4];
    gemm_rot4_128x8(A, Bt, K, row0, col0, acc);

    const int tid  = threadIdx.x;
    const int wv   = tid >> 6;
    const int lane = tid & 63;
    const int ln15 = lane & 15;
    const int lq   = lane >> 4;
    const int mbase = (wv >> 1) * 32;
    const int nbase = (wv & 1) * 64;

#pragma unroll
    for (int mi = 0; mi < 2; ++mi) {
#pragma unroll
        for (int ni = 0; ni < 4; ++ni) {
            const int gc = col0 + nbase + ni * 16 + ln15;
            const float bv = bias[gc];
#pragma unroll
            for (int r = 0; r < 4; ++r) {
                const int gr = row0 + mbase + mi * 16 + lq * 4 + r;
                float v = acc[mi][ni][r] + bv;
                if (act == 1) v = gelu_exact(v);
                if (residual) v += residual[(size_t)gr * N + gc];
                if (outBf16)
                    ((__hip_bfloat16*)Cout)[(size_t)gr * N + gc] = __float2bfloat16(v);
                else
                    ((float*)Cout)[(size_t)gr * N + gc] = v;
            }
        }
    }
}

// ---------------- qkv kernel (256x256 core) with routing epilogue
__global__ __launch_bounds__(512) void qkv256_kernel(
    const __hip_bfloat16* __restrict__ A,
    const __hip_bfloat16* __restrict__ Bt,
    const float* __restrict__ bias,
    __hip_bfloat16* __restrict__ Qb,
    __hip_bfloat16* __restrict__ Kb,
    __hip_bfloat16* __restrict__ Vtb)
{
    int bx, by;
    swz_xcd(bx, by);
    const int row0 = by * 256;
    const int col0 = bx * 256;

    f32x4 acc[8][4];
    gemm_rot4_512(A, Bt, D_MODEL, row0, col0, acc);

    const int tid  = threadIdx.x;
    const int wv   = tid >> 6;
    const int lane = tid & 63;
    const int ln15 = lane & 15;
    const int lq   = lane >> 4;
    const int mbase = (wv >> 2) * 128;
    const int nbase = (wv & 3) * 64;

#pragma unroll
    for (int mi = 0; mi < 8; ++mi) {
        const int gr0 = row0 + mbase + mi * 16 + lq * 4;   // + r
        const int bb  = gr0 >> 11;
        const int q0  = gr0 & 2047;
#pragma unroll
        for (int ni = 0; ni < 4; ++ni) {
            const int gc  = col0 + nbase + ni * 16 + ln15;
            const float bv = bias[gc];
            const int sec = gc >> 10;            // 0:Q 1:K 2:V
            const int hd  = (gc & 1023) >> 6;
            const int d   = gc & 63;
            if (sec == 2) {
                unsigned short u[4];
#pragma unroll
                for (int r = 0; r < 4; ++r) {
                    __hip_bfloat16 e = __float2bfloat16(acc[mi][ni][r] + bv);
                    u[r] = *(unsigned short*)&e;
                }
                uint2 pk;
                pk.x = (unsigned int)u[0] | ((unsigned int)u[1] << 16);
                pk.y = (unsigned int)u[2] | ((unsigned int)u[3] << 16);
                *(uint2*)(Vtb + ((size_t)((bb * N_HEAD + hd) * D_HEAD + d)) * SEQ_T + q0) = pk;
            } else {
                __hip_bfloat16* dst = (sec == 0 ? Qb : Kb)
                    + ((size_t)((bb * N_HEAD + hd) * SEQ_T + q0)) * D_HEAD + d;
#pragma unroll
                for (int r = 0; r < 4; ++r)
                    dst[(size_t)r * D_HEAD] = __float2bfloat16(acc[mi][ni][r] + bv);
            }
        }
    }
}

// ------------------------------------------------- MFMA flash attention v6
// As v5 (head-locality remap, reg-staged K/V double buffer) but LDS layouts
// rebuilt on measured-conflict-free patterns:
//   Ks: [half][128][32] (half = d/32), granule pos = c ^ ((row>>1)&3) —
//       the exact GEMM slice pattern (0 conflicts, R12).
//   Vts: [64][136] padded rows (272B -> row base advances 4 banks/row);
//       PV 8B reads become 2-way (free); writes 16B-aligned, no XOR.
#define ATQ 64
#define ATK 128
#define NQT (SEQ_T / ATQ)   // 32
#define VP2 136             // Vts row stride (elems)

__global__ __launch_bounds__(256) void mfma_attn_kernel(
    const __hip_bfloat16* __restrict__ Qb,
    const __hip_bfloat16* __restrict__ Kb,
    const __hip_bfloat16* __restrict__ Vtb,
    __hip_bfloat16* __restrict__ y)
{
    __shared__ __align__(16) __hip_bfloat16 Ks[2 * ATK * 32];   // [h][j][32] swz; O-scratch
    __shared__ __align__(16) __hip_bfloat16 Vts[D_HEAD * VP2];  // [d][j] padded

    // ---- head-locality remap: flat = (slot<<3)|xcd; slot = (hb<<4)|pair
    const int flat = (blockIdx.z * gridDim.y + blockIdx.y) * gridDim.x + blockIdx.x;
    const int xcd  = flat & 7;
    const int slot = flat >> 3;
    const int pair = slot & 15;          // 0..15
    const int hb   = slot >> 4;          // 0..3
    const int h    = xcd + 8 * (hb & 1);
    const int b    = hb >> 1;

    const int tid  = threadIdx.x;
    const int wv   = tid >> 6;
    const int lane = tid & 63;
    const int ln15 = lane & 15;
    const int lq   = lane >> 4;

    const __hip_bfloat16* Qh = Qb  + (size_t)(b * N_HEAD + h) * SEQ_T * D_HEAD;
    const __hip_bfloat16* Kh = Kb  + (size_t)(b * N_HEAD + h) * SEQ_T * D_HEAD;
    const __hip_bfloat16* Vh = Vtb + (size_t)(b * N_HEAD + h) * D_HEAD * SEQ_T;
    const size_t bT = (size_t)b * SEQ_T;

    const float CEXP = 0.18033688011f;   // 0.125 * log2(e)

    // staging registers (per-thread 1/4 of each tile row-chunk)
    bf16x8 kreg[4], vreg[4];
    const int kr = tid >> 3, kg = tid & 7;      // K: row base, 16B granule
    const int vr = tid >> 4, vc = tid & 15;     // V: row base, 16B granule
    const int khalf = kg >> 2;                  // d-half (0: 0-31, 1: 32-63)
    const int kpos  = (kg & 3) ^ ((kr >> 1) & 3);  // swizzled granule pos

    auto issue = [&](int kb) {
#pragma unroll
        for (int i = 0; i < 4; ++i)
            kreg[i] = *(const bf16x8*)(Kh + (size_t)(kb + kr + i * 32) * D_HEAD + kg * 8);
#pragma unroll
        for (int i = 0; i < 4; ++i)
            vreg[i] = *(const bf16x8*)(Vh + (size_t)(vr + i * 16) * SEQ_T + kb + vc * 8);
    };
    auto commit = [&]() {
#pragma unroll
        for (int i = 0; i < 4; ++i) {
            const int r = kr + i * 32;
            *(bf16x8*)&Ks[khalf * (ATK * 32) + r * 32 + kpos * 8] = kreg[i];
        }
#pragma unroll
        for (int i = 0; i < 4; ++i) {
            const int r = vr + i * 16;
            *(bf16x8*)&Vts[r * VP2 + vc * 8] = vreg[i];
        }
    };

    const int rcol = (lq ^ ((ln15 >> 1) & 3)) * 8;   // S^T read granule

#pragma unroll 1
    for (int half = 0; half < 2; ++half) {
        const int qt    = half == 0 ? pair : (NQT - 1 - pair);
        const int qbase = qt * ATQ;
        const int ntk   = (qt >> 1) + 1;
        const int qg    = qbase + wv * 16 + ln15;   // stats-owner q row

        bf16x8 qf[2];
#pragma unroll
        for (int kc = 0; kc < 2; ++kc)
            qf[kc] = *(const bf16x8*)(Qh + (size_t)(qbase + wv * 16 + ln15) * D_HEAD
                                      + kc * 32 + lq * 8);

        f32x4 Oacc[4];
#pragma unroll
        for (int dn = 0; dn < 4; ++dn) Oacc[dn] = (f32x4){0.f, 0.f, 0.f, 0.f};
        float m_run = -INFINITY, l_run = 0.f;

        issue(0);

        for (int t = 0; t < ntk; ++t) {
            const int kb = t * ATK;
            commit();                       // regs(t) -> LDS (auto vmcnt wait)
            __syncthreads();                // writes visible to all waves
            if (t + 1 < ntk) issue((t + 1) * ATK);   // prefetch under compute

            // ---- S^T[j=128][q=16] : A=K (rows j), B=Q (rows q), 16x16x32
            f32x4 st[8];
#pragma unroll
            for (int jf = 0; jf < 8; ++jf) st[jf] = (f32x4){0.f, 0.f, 0.f, 0.f};
            __builtin_amdgcn_s_setprio(1);
#pragma unroll
            for (int jf = 0; jf < 8; ++jf) {
                const int rw = jf * 16 + ln15;
                const bf16x8 kf0 = *(const bf16x8*)&Ks[rw * 32 + rcol];
                const bf16x8 kf1 = *(const bf16x8*)&Ks[ATK * 32 + rw * 32 + rcol];
                st[jf] = __builtin_amdgcn_mfma_f32_16x16x32_bf16(kf0, qf[0], st[jf], 0, 0, 0);
                st[jf] = __builtin_amdgcn_mfma_f32_16x16x32_bf16(kf1, qf[1], st[jf], 0, 0, 0);
            }
            __builtin_amdgcn_s_setprio(0);

            // ---- causal mask on the diagonal tile (raw-score domain)
            if (t == ntk - 1) {
#pragma unroll
                for (int jf = 0; jf < 8; ++jf)
#pragma unroll
                    for (int r = 0; r < 4; ++r)
                        if ((kb + jf * 16 + lq * 4 + r) > qg) st[jf][r] = -INFINITY;
            }

            // ---- online softmax for q=qg (raw max; exp2 with folded scale)
            float tmax = st[0][0];
#pragma unroll
            for (int jf = 0; jf < 8; ++jf)
#pragma unroll
                for (int r = 0; r < 4; ++r) tmax = fmaxf(tmax, st[jf][r]);
            tmax = fmaxf(tmax, __shfl_xor(tmax, 16));
            tmax = fmaxf(tmax, __shfl_xor(tmax, 32));
            const float mnew  = fmaxf(m_run, tmax);
            const float alpha = exp2f((m_run - mnew) * CEXP);
            const float mc    = mnew * CEXP;
            float psum = 0.f;
#pragma unroll
            for (int jf = 0; jf < 8; ++jf)
#pragma unroll
                for (int r = 0; r < 4; ++r) {
                    const float p = exp2f(fmaf(st[jf][r], CEXP, -mc));
                    st[jf][r] = p;
                    psum += p;
                }
            psum += __shfl_xor(psum, 16);
            psum += __shfl_xor(psum, 32);
            l_run = alpha * l_run + psum;
            m_run = mnew;

            float a4[4];
#pragma unroll
            for (int r = 0; r < 4; ++r) a4[r] = __shfl(alpha, lq * 4 + r);
#pragma unroll
            for (int dn = 0; dn < 4; ++dn)
#pragma unroll
                for (int r = 0; r < 4; ++r) Oacc[dn][r] *= a4[r];

            // ---- O += P V via 16x16x16: P-frag is the S^T C-fragment
            __builtin_amdgcn_s_setprio(1);
#pragma unroll
            for (int jf = 0; jf < 8; ++jf) {
                s16x4 pfr;
#pragma unroll
                for (int s = 0; s < 4; ++s) {
                    __hip_bfloat16 e = __float2bfloat16(st[jf][s]);
                    pfr[s] = __builtin_bit_cast(short, e);
                }
#pragma unroll
                for (int dn = 0; dn < 4; ++dn) {
                    const s16x4 vfr = *(const s16x4*)&Vts[(dn * 16 + ln15) * VP2
                                                          + jf * 16 + lq * 4];
                    Oacc[dn] = mfma16_bf16(pfr, vfr, Oacc[dn]);
                }
            }
            __builtin_amdgcn_s_setprio(0);
            __syncthreads();                // all reads done before next commit
        }

        // ---- epilogue: transpose O through Ks scratch (all reads barriered)
        float il[4];
#pragma unroll
        for (int r = 0; r < 4; ++r) il[r] = 1.0f / __shfl(l_run, lq * 4 + r);
#pragma unroll
        for (int dn = 0; dn < 4; ++dn)
#pragma unroll
            for (int r = 0; r < 4; ++r)
                Ks[(wv * 16 + lq * 4 + r) * 72 + dn * 16 + ln15] =
                    __float2bfloat16(Oacc[dn][r] * il[r]);
        const int r2 = lane >> 3, c8 = (lane & 7) * 8;
#pragma unroll
        for (int i = 0; i < 2; ++i) {
            const int row = wv * 16 + r2 + 8 * i;
            const bf16x8 val = *(const bf16x8*)&Ks[row * 72 + c8];
            *(bf16x8*)(y + (bT + qbase + row) * D_MODEL + h * D_HEAD + c8) = val;
        }
        __syncthreads();                    // Ks scratch free before next half
    }
}

// ------------------------------------------------------------------ launch
extern "C" void kernel_launch(void* const* d_in, const int* in_sizes, int n_in,
                              void* d_out, int out_size, void* d_ws, size_t ws_size,
                              hipStream_t stream)
{
    const float* x      = (const float*)d_in[0];
    const float* ln1_w  = (const float*)d_in[1];
    const float* ln1_b  = (const float*)d_in[2];
    const float* attn_w = (const float*)d_in[3];
    const float* attn_b = (const float*)d_in[4];
    const float* proj_w = (const float*)d_in[5];
    const float* proj_b = (const float*)d_in[6];
    const float* ln2_w  = (const float*)d_in[7];
    const float* ln2_b  = (const float*)d_in[8];
    const float* fc_w   = (const float*)d_in[9];
    const float* fc_b   = (const float*)d_in[10];
    const float* fc2_w  = (const float*)d_in[11];
    const float* fc2_b  = (const float*)d_in[12];
    float* out = (float*)d_out;

    char* ws = (char*)d_ws;
    __hip_bfloat16* Qb      = (__hip_bfloat16*)(ws);
    __hip_bfloat16* Kb      = (__hip_bfloat16*)(ws + (size_t)8  * 1024 * 1024);
    __hip_bfloat16* Vtb     = (__hip_bfloat16*)(ws + (size_t)16 * 1024 * 1024);
    __hip_bfloat16* h_bf    = (__hip_bfloat16*)(ws);
    __hip_bfloat16* ln_buf  = (__hip_bfloat16*)(ws + (size_t)32 * 1024 * 1024);
    __hip_bfloat16* y_buf   = (__hip_bfloat16*)(ws + (size_t)40 * 1024 * 1024);
    float*          xmid    = (float*)(ws + (size_t)48 * 1024 * 1024);
    __hip_bfloat16* attn_wt = (__hip_bfloat16*)(ws + (size_t)64 * 1024 * 1024);
    __hip_bfloat16* proj_wt = (__hip_bfloat16*)(ws + (size_t)70 * 1024 * 1024);
    __hip_bfloat16* fc_wt   = (__hip_bfloat16*)(ws + (size_t)72 * 1024 * 1024);
    __hip_bfloat16* fc2_wt  = (__hip_bfloat16*)(ws + (size_t)80 * 1024 * 1024);

    dim3 blk256(256);
    dim3 blk512(512);

    // 0. all weight transposes in one launch (fp32 [K,N] -> bf16 [N,K])
    transpose_all_kernel<<<dim3(12288), blk256, 0, stream>>>(
        attn_w, proj_w, fc_w, fc2_w, attn_wt, proj_wt, fc_wt, fc2_wt);

    // 1. ln1(x) -> ln_buf (bf16)
    ln_kernel<<<dim3(NROWS), blk256, 0, stream>>>(x, ln1_w, ln1_b, ln_buf, D_MODEL);

    // 2. qkv GEMM (rot4 256x256) -> Qb/Kb/Vtb   grid 12x16 = 192
    qkv256_kernel<<<dim3(C3 / 256, NROWS / 256), blk512, 0, stream>>>(
        ln_buf, attn_wt, attn_b, Qb, Kb, Vtb);

    // 3. MFMA flash attention v6 -> y_buf (bf16)
    mfma_attn_kernel<<<dim3(NQT / 2, N_HEAD, BATCH), blk256, 0, stream>>>(
        Qb, Kb, Vtb, y_buf);

    // 4. xmid = x + y_buf @ proj_w + proj_b  (fp32, 8-wave 128x128, grid 256)
    gemm128_kernel<<<dim3(D_MODEL / 128, NROWS / 128), blk512, 0, stream>>>(
        y_buf, proj_wt, proj_b, x, xmid, NROWS, D_MODEL, D_MODEL, 0, 0);

    // 5. ln2(xmid) -> ln_buf (bf16)
    ln_kernel<<<dim3(NROWS), blk256, 0, stream>>>(xmid, ln2_w, ln2_b, ln_buf, D_MODEL);

    // 6. h = gelu(ln_buf @ fc_w + fc_b) -> bf16 (rot4 256x256, grid 256)
    gemm256_kernel<<<dim3(D_FF / 256, NROWS / 256), blk512, 0, stream>>>(
        ln_buf, fc_wt, fc_b, nullptr, h_bf, NROWS, D_FF, D_MODEL, 1, 1);

    // 7. out = xmid + h @ fc2_w + fc2_b  (fp32, 8-wave 128x128, grid 256)
    gemm128_kernel<<<dim3(D_MODEL / 128, NROWS / 128), blk512, 0, stream>>>(
        h_bf, fc2_wt, fc2_b, xmid, out, NROWS, D_MODEL, D_FF, 0, 0);
}